// Round 20
// baseline (232.484 us; speedup 1.0000x reference)
//
#include <hip/hip_runtime.h>
#include <hip/hip_bf16.h>
#include <hip/hip_fp16.h>
#include <math.h>

#define B_ 4
#define L_ 2048
#define E_ 1024
#define H_ 16
#define D_ 64
#define NFFT 4096
#define CAP 128

typedef __hip_bfloat16 bf16;
typedef __attribute__((ext_vector_type(8))) short bf16x8;
typedef __attribute__((ext_vector_type(4))) float f32x4;
typedef __attribute__((ext_vector_type(2))) __fp16 f16x2;

typedef __attribute__((address_space(1))) const unsigned int gas_u32;
typedef __attribute__((address_space(3))) unsigned int las_u32;

__device__ __forceinline__ void gload_lds16(const void* g, void* l) {
    __builtin_amdgcn_global_load_lds((gas_u32*)g, (las_u32*)l, 16, 0, 0);
}

// padded LDS slot: +1 per 16 (<=2-way conflicts for all 3 phase patterns)
#define SL(i) ((i) + ((i) >> 4))
#define LDSN (NFFT + NFFT / 16)   // 4352

__device__ __forceinline__ float bfu2f(unsigned short u) {
    return __uint_as_float(((unsigned)u) << 16);
}
__device__ __forceinline__ f16x2 pk2(float a, float b) {
    return __builtin_amdgcn_cvt_pkrtz(a, b);
}

// base-4 3-digit reversal (involution)
__device__ __forceinline__ int drev64(int k) {
    return ((k & 3) << 4) | (k & 12) | ((k >> 4) & 3);
}

// stage-1 constants: C[j] = tw[256*j] = exp(-i*pi*j/8)
#define C1R 0.923879532511287f
#define C1I -0.382683432365090f
#define C2R 0.707106781186548f
#define C2I -0.707106781186548f
#define C3R 0.382683432365090f
#define C3I -0.923879532511287f

// ------- register radix-4 butterflies; w2=w1^2, w3=w1^3 derived in-reg -------
__device__ __forceinline__ void r4dif_w(float& x0r, float& x0i, float& x1r, float& x1i,
                                        float& x2r, float& x2i, float& x3r, float& x3i,
                                        float w1r, float w1i) {
    float a0r = x0r + x2r, a0i = x0i + x2i, a1r = x0r - x2r, a1i = x0i - x2i;
    float a2r = x1r + x3r, a2i = x1i + x3i, a3r = x1r - x3r, a3i = x1i - x3i;
    float y0r = a0r + a2r, y0i = a0i + a2i, y2r = a0r - a2r, y2i = a0i - a2i;
    float y1r = a1r + a3i, y1i = a1i - a3r, y3r = a1r - a3i, y3i = a1i + a3r;
    float w2r = w1r * w1r - w1i * w1i, w2i = 2.0f * w1r * w1i;
    float w3r = w2r * w1r - w2i * w1i, w3i = w2r * w1i + w2i * w1r;
    x0r = y0r; x0i = y0i;
    x1r = y1r * w1r - y1i * w1i; x1i = y1r * w1i + y1i * w1r;
    x2r = y2r * w2r - y2i * w2i; x2i = y2r * w2i + y2i * w2r;
    x3r = y3r * w3r - y3i * w3i; x3i = y3r * w3i + y3i * w3r;
}
__device__ __forceinline__ void r4dif_nt(float& x0r, float& x0i, float& x1r, float& x1i,
                                         float& x2r, float& x2i, float& x3r, float& x3i) {
    float a0r = x0r + x2r, a0i = x0i + x2i, a1r = x0r - x2r, a1i = x0i - x2i;
    float a2r = x1r + x3r, a2i = x1i + x3i, a3r = x1r - x3r, a3i = x1i - x3i;
    x0r = a0r + a2r; x0i = a0i + a2i;
    x2r = a0r - a2r; x2i = a0i - a2i;
    float y1r = a1r + a3i, y1i = a1i - a3r, y3r = a1r - a3i, y3i = a1i + a3r;
    x1r = y1r; x1i = y1i; x3r = y3r; x3i = y3i;
}
__device__ __forceinline__ void r4dit_w(float& x0r, float& x0i, float& x1r, float& x1i,
                                        float& x2r, float& x2i, float& x3r, float& x3i,
                                        float w1r, float w1i) {
    float w2r = w1r * w1r - w1i * w1i, w2i = 2.0f * w1r * w1i;
    float w3r = w2r * w1r - w2i * w1i, w3i = w2r * w1i + w2i * w1r;
    float z1r = x1r * w1r + x1i * w1i, z1i = x1i * w1r - x1r * w1i;
    float z2r = x2r * w2r + x2i * w2i, z2i = x2i * w2r - x2r * w2i;
    float z3r = x3r * w3r + x3i * w3i, z3i = x3i * w3r - x3r * w3i;
    float b0r = x0r + z2r, b0i = x0i + z2i, b1r = x0r - z2r, b1i = x0i - z2i;
    float b2r = z1r + z3r, b2i = z1i + z3i, b3r = z1r - z3r, b3i = z1i - z3i;
    x0r = b0r + b2r; x0i = b0i + b2i;
    x2r = b0r - b2r; x2i = b0i - b2i;
    x1r = b1r - b3i; x1i = b1i + b3r;
    x3r = b1r + b3i; x3i = b1i - b3r;
}
__device__ __forceinline__ void r4dit_nt(float& x0r, float& x0i, float& x1r, float& x1i,
                                         float& x2r, float& x2i, float& x3r, float& x3i) {
    float b0r = x0r + x2r, b0i = x0i + x2i, b1r = x0r - x2r, b1i = x0i - x2i;
    float b2r = x1r + x3r, b2i = x1i + x3i, b3r = x1r - x3r, b3i = x1i - x3i;
    x0r = b0r + b2r; x0i = b0i + b2i;
    x2r = b0r - b2r; x2i = b0i - b2i;
    x1r = b1r - b3i; x1i = b1i + b3r;
    x3r = b1r + b3i; x3i = b1i - b3r;
}

// ---- phase A (stages 0,1): thread p owns X[j]=a[p+256j]; wp = tw[p] ---------
__device__ __forceinline__ void fftA_fwd(float* xr, float* xi, float wpr, float wpi) {
    r4dif_w(xr[0], xi[0], xr[4], xi[4], xr[8], xi[8], xr[12], xi[12], wpr, wpi);
    r4dif_w(xr[1], xi[1], xr[5], xi[5], xr[9], xi[9], xr[13], xi[13],
            wpr * C1R - wpi * C1I, wpr * C1I + wpi * C1R);
    r4dif_w(xr[2], xi[2], xr[6], xi[6], xr[10], xi[10], xr[14], xi[14],
            wpr * C2R - wpi * C2I, wpr * C2I + wpi * C2R);
    r4dif_w(xr[3], xi[3], xr[7], xi[7], xr[11], xi[11], xr[15], xi[15],
            wpr * C3R - wpi * C3I, wpr * C3I + wpi * C3R);
    float s2r = wpr * wpr - wpi * wpi, s2i = 2.0f * wpr * wpi;
    float w4r = s2r * s2r - s2i * s2i, w4i = 2.0f * s2r * s2i;
#pragma unroll
    for (int g = 0; g < 4; ++g)
        r4dif_w(xr[4 * g], xi[4 * g], xr[4 * g + 1], xi[4 * g + 1], xr[4 * g + 2],
                xi[4 * g + 2], xr[4 * g + 3], xi[4 * g + 3], w4r, w4i);
}
__device__ __forceinline__ void fftA_inv(float* xr, float* xi, float wpr, float wpi) {
    float s2r = wpr * wpr - wpi * wpi, s2i = 2.0f * wpr * wpi;
    float w4r = s2r * s2r - s2i * s2i, w4i = 2.0f * s2r * s2i;
#pragma unroll
    for (int g = 0; g < 4; ++g)
        r4dit_w(xr[4 * g], xi[4 * g], xr[4 * g + 1], xi[4 * g + 1], xr[4 * g + 2],
                xi[4 * g + 2], xr[4 * g + 3], xi[4 * g + 3], w4r, w4i);
    r4dit_w(xr[0], xi[0], xr[4], xi[4], xr[8], xi[8], xr[12], xi[12], wpr, wpi);
    r4dit_w(xr[1], xi[1], xr[5], xi[5], xr[9], xi[9], xr[13], xi[13],
            wpr * C1R - wpi * C1I, wpr * C1I + wpi * C1R);
    r4dit_w(xr[2], xi[2], xr[6], xi[6], xr[10], xi[10], xr[14], xi[14],
            wpr * C2R - wpi * C2I, wpr * C2I + wpi * C2R);
    r4dit_w(xr[3], xi[3], xr[7], xi[7], xr[11], xi[11], xr[15], xi[15],
            wpr * C3R - wpi * C3I, wpr * C3I + wpi * C3R);
}
// ---- phase B (stages 2,3): thread (b,o) owns X[j]=a[b*256+o+16j]; wo=tw[16o]
__device__ __forceinline__ void fftB_fwd(float* xr, float* xi, float wor, float woi) {
    r4dif_w(xr[0], xi[0], xr[4], xi[4], xr[8], xi[8], xr[12], xi[12], wor, woi);
    r4dif_w(xr[1], xi[1], xr[5], xi[5], xr[9], xi[9], xr[13], xi[13],
            wor * C1R - woi * C1I, wor * C1I + woi * C1R);
    r4dif_w(xr[2], xi[2], xr[6], xi[6], xr[10], xi[10], xr[14], xi[14],
            wor * C2R - woi * C2I, wor * C2I + woi * C2R);
    r4dif_w(xr[3], xi[3], xr[7], xi[7], xr[11], xi[11], xr[15], xi[15],
            wor * C3R - woi * C3I, wor * C3I + woi * C3R);
    float s2r = wor * wor - woi * woi, s2i = 2.0f * wor * woi;
    float w4r = s2r * s2r - s2i * s2i, w4i = 2.0f * s2r * s2i;
#pragma unroll
    for (int g = 0; g < 4; ++g)
        r4dif_w(xr[4 * g], xi[4 * g], xr[4 * g + 1], xi[4 * g + 1], xr[4 * g + 2],
                xi[4 * g + 2], xr[4 * g + 3], xi[4 * g + 3], w4r, w4i);
}
__device__ __forceinline__ void fftB_inv(float* xr, float* xi, float wor, float woi) {
    float s2r = wor * wor - woi * woi, s2i = 2.0f * wor * woi;
    float w4r = s2r * s2r - s2i * s2i, w4i = 2.0f * s2r * s2i;
#pragma unroll
    for (int g = 0; g < 4; ++g)
        r4dit_w(xr[4 * g], xi[4 * g], xr[4 * g + 1], xi[4 * g + 1], xr[4 * g + 2],
                xi[4 * g + 2], xr[4 * g + 3], xi[4 * g + 3], w4r, w4i);
    r4dit_w(xr[0], xi[0], xr[4], xi[4], xr[8], xi[8], xr[12], xi[12], wor, woi);
    r4dit_w(xr[1], xi[1], xr[5], xi[5], xr[9], xi[9], xr[13], xi[13],
            wor * C1R - woi * C1I, wor * C1I + woi * C1R);
    r4dit_w(xr[2], xi[2], xr[6], xi[6], xr[10], xi[10], xr[14], xi[14],
            wor * C2R - woi * C2I, wor * C2I + woi * C2R);
    r4dit_w(xr[3], xi[3], xr[7], xi[7], xr[11], xi[11], xr[15], xi[15],
            wor * C3R - woi * C3I, wor * C3I + woi * C3R);
}
// ---- phase C (stages 4,5): thread t owns X[j]=a[16t+j]; constant twiddles ---
__device__ __forceinline__ void fftC_fwd(float* xr, float* xi) {
    r4dif_w(xr[0], xi[0], xr[4], xi[4], xr[8], xi[8], xr[12], xi[12], 1.0f, 0.0f);
    r4dif_w(xr[1], xi[1], xr[5], xi[5], xr[9], xi[9], xr[13], xi[13], C1R, C1I);
    r4dif_w(xr[2], xi[2], xr[6], xi[6], xr[10], xi[10], xr[14], xi[14], C2R, C2I);
    r4dif_w(xr[3], xi[3], xr[7], xi[7], xr[11], xi[11], xr[15], xi[15], C3R, C3I);
#pragma unroll
    for (int g = 0; g < 4; ++g)
        r4dif_nt(xr[4 * g], xi[4 * g], xr[4 * g + 1], xi[4 * g + 1], xr[4 * g + 2],
                 xi[4 * g + 2], xr[4 * g + 3], xi[4 * g + 3]);
}
__device__ __forceinline__ void fftC_inv(float* xr, float* xi) {
#pragma unroll
    for (int g = 0; g < 4; ++g)
        r4dit_nt(xr[4 * g], xi[4 * g], xr[4 * g + 1], xi[4 * g + 1], xr[4 * g + 2],
                 xi[4 * g + 2], xr[4 * g + 3], xi[4 * g + 3]);
    r4dit_w(xr[0], xi[0], xr[4], xi[4], xr[8], xi[8], xr[12], xi[12], 1.0f, 0.0f);
    r4dit_w(xr[1], xi[1], xr[5], xi[5], xr[9], xi[9], xr[13], xi[13], C1R, C1I);
    r4dit_w(xr[2], xi[2], xr[6], xi[6], xr[10], xi[10], xr[14], xi[14], C2R, C2I);
    r4dit_w(xr[3], xi[3], xr[7], xi[7], xr[11], xi[11], xr[15], xi[15], C3R, C3I);
}

// ---- batched 64-pt radix-4 over rows, LDS layout idx = row*66 + col ---------
template <int CONJ>
__device__ inline void fft64_rows(float* xr, float* xi, int tid,
                                  const float2* __restrict__ tw) {
    for (int st = 0; st < 3; ++st) {
        int q = 1 << (4 - 2 * st);
        __syncthreads();
        for (int it = 0; it < 4; ++it) {
            int w = tid + (it << 8);
            int lc = w & 63, bc = w >> 6;
            int p = bc & (q - 1);
            int basev = ((bc & ~(q - 1)) << 2) | p;
            int i0 = basev * 66 + lc, i1 = i0 + q * 66, i2 = i1 + q * 66, i3 = i2 + q * 66;
            float x0r = xr[i0], x0i = xi[i0], x1r = xr[i1], x1i = xi[i1];
            float x2r = xr[i2], x2i = xi[i2], x3r = xr[i3], x3i = xi[i3];
            float a0r = x0r + x2r, a0i = x0i + x2i;
            float a1r = x0r - x2r, a1i = x0i - x2i;
            float a2r = x1r + x3r, a2i = x1i + x3i;
            float a3r = x1r - x3r, a3i = x1i - x3i;
            float y0r = a0r + a2r, y0i = a0i + a2i;
            float y2r = a0r - a2r, y2i = a0i - a2i;
            float y1r, y1i, y3r, y3i;
            if (!CONJ) {
                y1r = a1r + a3i; y1i = a1i - a3r;
                y3r = a1r - a3i; y3i = a1i + a3r;
            } else {
                y1r = a1r - a3i; y1i = a1i + a3r;
                y3r = a1r + a3i; y3i = a1i - a3r;
            }
            int e = (p << (2 * st)) * 64;
            float2 w1 = tw[e];
            float w1x = w1.x, w1y = CONJ ? -w1.y : w1.y;
            float w2x = w1x * w1x - w1y * w1y, w2y = 2.0f * w1x * w1y;
            float w3x = w2x * w1x - w2y * w1y, w3y = w2x * w1y + w2y * w1x;
            xr[i0] = y0r; xi[i0] = y0i;
            xr[i1] = y1r * w1x - y1i * w1y; xi[i1] = y1r * w1y + y1i * w1x;
            xr[i2] = y2r * w2x - y2i * w2y; xi[i2] = y2r * w2y + y2i * w2x;
            xr[i3] = y3r * w3x - y3i * w3y; xi[i3] = y3r * w3y + y3i * w3x;
        }
    }
    __syncthreads();
}

// ------- batched 64-pt radix-4 FFT over rows in [row*64+col] layout ----------
__device__ inline void fft64_b(float* xr, float* xi, int tid,
                               const float2* __restrict__ tw) {
    for (int st = 0; st < 3; ++st) {
        int q = 1 << (4 - 2 * st);
        __syncthreads();
        for (int it = 0; it < 4; ++it) {
            int b = tid + (it << 8);
            int fc = b & 63;
            int bc = b >> 6;
            int p = bc & (q - 1);
            int basev = ((bc & ~(q - 1)) << 2) | p;
            int i0 = basev * 64 + fc, i1 = i0 + q * 64, i2 = i1 + q * 64, i3 = i2 + q * 64;
            float x0r = xr[i0], x0i = xi[i0], x1r = xr[i1], x1i = xi[i1];
            float x2r = xr[i2], x2i = xi[i2], x3r = xr[i3], x3i = xi[i3];
            float a0r = x0r + x2r, a0i = x0i + x2i;
            float a1r = x0r - x2r, a1i = x0i - x2i;
            float a2r = x1r + x3r, a2i = x1i + x3i;
            float a3r = x1r - x3r, a3i = x1i - x3i;
            float y0r = a0r + a2r, y0i = a0i + a2i;
            float y2r = a0r - a2r, y2i = a0i - a2i;
            float y1r = a1r + a3i, y1i = a1i - a3r;
            float y3r = a1r - a3i, y3i = a1i + a3r;
            int e = (p << (2 * st)) * 64;
            float2 w1 = tw[e];
            float w2x = w1.x * w1.x - w1.y * w1.y, w2y = 2.0f * w1.x * w1.y;
            float w3x = w2x * w1.x - w2y * w1.y, w3y = w2x * w1.y + w2y * w1.x;
            xr[i0] = y0r; xi[i0] = y0i;
            xr[i1] = y1r * w1.x - y1i * w1.y; xi[i1] = y1r * w1.y + y1i * w1.x;
            xr[i2] = y2r * w2x - y2i * w2y; xi[i2] = y2r * w2y + y2i * w2x;
            xr[i3] = y3r * w3x - y3i * w3y; xi[i3] = y3r * w3y + y3i * w3x;
        }
    }
    __syncthreads();
}

// ---- merged prologue: twiddle | emb cvt | W cvt | psf transpose | sparse ----
#define NB_TW 16
#define NB_CVT 8192
#define NB_CVTW 3072
#define NB_TF 512
#define NB_SP 2048
__global__ __launch_bounds__(256) void k_prologue(const float* __restrict__ emb,
                                                  const float* __restrict__ W1,
                                                  const float* __restrict__ W2,
                                                  const float* __restrict__ W3,
                                                  const float* __restrict__ psfs,
                                                  const float* __restrict__ Sp,
                                                  float2* __restrict__ tw,
                                                  bf16* __restrict__ embb,
                                                  bf16* __restrict__ Wb,
                                                  float* __restrict__ psfT,
                                                  int* __restrict__ nnz,
                                                  int* __restrict__ idxs,
                                                  float* __restrict__ vals) {
    __shared__ float tile[64][65];
    __shared__ int cnt;
    int tid = threadIdx.x;
    int blk = blockIdx.x;
    if (blk < NB_TW) {
        int k = blk * 256 + tid;
        float ang = -(float)k * (float)(M_PI / 2048.0);
        tw[k] = make_float2(cosf(ang), sinf(ang));
        return;
    }
    blk -= NB_TW;
    if (blk < NB_CVT) {
        int i = (blk * 256 + tid) * 4;
        float4 v = *(const float4*)(emb + i);
        bf16 tmp[4];
        tmp[0] = __float2bfloat16(v.x); tmp[1] = __float2bfloat16(v.y);
        tmp[2] = __float2bfloat16(v.z); tmp[3] = __float2bfloat16(v.w);
        *(ushort4*)(embb + i) = *(ushort4*)tmp;
        return;
    }
    blk -= NB_CVT;
    if (blk < NB_CVTW) {
        int w = blk >> 10;
        const float* src = (w == 0) ? W1 : (w == 1) ? W2 : W3;
        int i = ((blk & 1023) * 256 + tid) * 4;
        float4 v = *(const float4*)(src + i);
        bf16 tmp[4];
        tmp[0] = __float2bfloat16(v.x); tmp[1] = __float2bfloat16(v.y);
        tmp[2] = __float2bfloat16(v.z); tmp[3] = __float2bfloat16(v.w);
        *(ushort4*)(Wb + (size_t)w * E_ * E_ + i) = *(ushort4*)tmp;
        return;
    }
    blk -= NB_CVTW;
    if (blk < NB_TF) {
        int z = blk >> 5;
        int r0 = (blk & 31) * 64;
        const float* in = psfs + (size_t)z * (2 * L_ - 1) * D_;
        float* out = psfT + (size_t)z * D_ * L_;
        int tx4 = (tid & 15) * 4, ty = tid >> 4;
#pragma unroll
        for (int k = 0; k < 4; ++k) {
            int r = ty + 16 * k;
            float4 v = *(const float4*)&in[(size_t)(r0 + r) * D_ + tx4];
            tile[r][tx4 + 0] = v.x; tile[r][tx4 + 1] = v.y;
            tile[r][tx4 + 2] = v.z; tile[r][tx4 + 3] = v.w;
        }
        __syncthreads();
#pragma unroll
        for (int k = 0; k < 4; ++k) {
            int c = ty + 16 * k;
            float4 w;
            w.x = tile[tx4 + 0][c]; w.y = tile[tx4 + 1][c];
            w.z = tile[tx4 + 2][c]; w.w = tile[tx4 + 3][c];
            *(float4*)&out[(size_t)c * L_ + r0 + tx4] = w;
        }
        return;
    }
    blk -= NB_TF;
    {
        int l = blk;
        if (tid == 0) cnt = 0;
        __syncthreads();
        const float* row = Sp + (size_t)l * L_;
        for (int s = tid; s <= l; s += 256) {
            float v = row[s];
            if (v != 0.0f) {
                int slot = atomicAdd(&cnt, 1);
                if (slot < CAP) { idxs[l * CAP + slot] = s; vals[l * CAP + slot] = v; }
            }
        }
        __syncthreads();
        if (tid == 0) nnz[l] = min(cnt, CAP);
    }
}

// ---- GEMM body (64x128 tile, BK=64, swizzled LDS, XCD swizzle), bf16 out ----
__device__ __forceinline__ void gemm_body(void* smemraw, int flat, int nwgx,
                                          const bf16* __restrict__ A,
                                          const bf16* __restrict__ Wt,
                                          const float* __restrict__ bias,
                                          bf16* __restrict__ Cb,
                                          int nwg, int N, int K) {
    bf16* As = (bf16*)smemraw;        // 64*64
    bf16* Bs = As + 64 * 64;          // 128*64
    int tid = threadIdx.x;
    int lane = tid & 63, w = tid >> 6;
    int wr = w >> 1, wc = w & 1;

    int cpx = nwg >> 3;
    int swz = (flat & 7) * cpx + (flat >> 3);
    int bx = (swz % nwgx) * 128;
    int by = (swz / nwgx) * 64;

    f32x4 zz = {0.0f, 0.0f, 0.0f, 0.0f};
    f32x4 acc[2][4];
#pragma unroll
    for (int m = 0; m < 2; ++m)
#pragma unroll
        for (int n = 0; n < 4; ++n) acc[m][n] = zz;

    int koff = (lane >> 4) * 8;
    int rsub = lane & 15;

    for (int k0 = 0; k0 < K; k0 += 64) {
#pragma unroll
        for (int i = 0; i < 2; ++i) {
            int c = tid + i * 256;
            int row = c >> 3;
            int kb = (c & 7) * 8;
            int kbs = kb ^ ((row & 7) << 3);
            gload_lds16(A + (size_t)(by + row) * K + k0 + kbs, &As[c * 8]);
        }
#pragma unroll
        for (int i = 0; i < 4; ++i) {
            int c = tid + i * 256;
            int row = c >> 3;
            int kb = (c & 7) * 8;
            int kbs = kb ^ ((row & 7) << 3);
            gload_lds16(Wt + (size_t)(bx + row) * K + k0 + kbs, &Bs[c * 8]);
        }
        __syncthreads();
#pragma unroll
        for (int half = 0; half < 2; ++half) {
            int ko = koff + half * 32;
            bf16x8 af[2], bfv[4];
#pragma unroll
            for (int m = 0; m < 2; ++m) {
                int R = wr * 32 + m * 16 + rsub;
                af[m] = *(const bf16x8*)&As[R * 64 + (ko ^ ((R & 7) << 3))];
            }
#pragma unroll
            for (int n = 0; n < 4; ++n) {
                int R = wc * 64 + n * 16 + rsub;
                bfv[n] = *(const bf16x8*)&Bs[R * 64 + (ko ^ ((R & 7) << 3))];
            }
#pragma unroll
            for (int m = 0; m < 2; ++m)
#pragma unroll
                for (int n = 0; n < 4; ++n)
                    acc[m][n] = __builtin_amdgcn_mfma_f32_16x16x32_bf16(af[m], bfv[n], acc[m][n], 0, 0, 0);
        }
        __syncthreads();
    }

    int cq = (lane >> 4) * 4;
    int cr = lane & 15;
#pragma unroll
    for (int m = 0; m < 2; ++m) {
        int row0 = by + wr * 32 + m * 16 + cq;
#pragma unroll
        for (int n = 0; n < 4; ++n) {
            int col = bx + wc * 64 + n * 16 + cr;
            float bv = bias[col];
#pragma unroll
            for (int j = 0; j < 4; ++j) {
                float v = acc[m][n][j] + bv;
                Cb[(size_t)(row0 + j) * N + col] = __float2bfloat16(v);
            }
        }
    }
}

// ---- build_khat body: PSF softmax + FULL K4096 + fwd FFT --------------------
__device__ __forceinline__ void khat_body(void* smemraw, int blk,
                                          const float* __restrict__ psfT,
                                          f16x2* __restrict__ Khat,
                                          const float2* __restrict__ tw) {
    f16x2* fl = (f16x2*)smemraw;
    float* red = (float*)(fl + LDSN);
    int u = blk & 63, h = blk >> 6;
    int tid = threadIdx.x;
    const float* col = psfT + ((size_t)(h * D_ + u)) * L_;
    int p = tid;

    float2 twp = tw[p];
    float2 two = tw[(tid & 15) * 16];

    float v[8];
#pragma unroll
    for (int j = 0; j < 8; ++j) v[j] = col[p + 256 * j];

    float lm = v[0];
#pragma unroll
    for (int j = 1; j < 8; ++j) lm = fmaxf(lm, v[j]);
    red[tid] = lm; __syncthreads();
    for (int off = 128; off > 0; off >>= 1) {
        if (tid < off) red[tid] = fmaxf(red[tid], red[tid + off]);
        __syncthreads();
    }
    float M = fmaxf(red[0], 0.0f);
    __syncthreads();

    float e[8];
    float ls = 0.0f;
#pragma unroll
    for (int j = 0; j < 8; ++j) { e[j] = expf(v[j] - M); ls += e[j]; }
    red[tid] = ls; __syncthreads();
    for (int off = 128; off > 0; off >>= 1) {
        if (tid < off) red[tid] += red[tid + off];
        __syncthreads();
    }
    float Z = red[0] + (float)(L_ - 1) * expf(-M);
    float invZ = 1.0f / Z;
    float cval = expf(-M) * invZ;

    float xr[16], xi[16];
#pragma unroll
    for (int j = 0; j < 16; ++j) {
        int i = p + 256 * j;
        xr[j] = (j < 8) ? e[j] * invZ : ((i == 2048) ? 0.0f : cval);
        xi[j] = 0.0f;
    }
    __syncthreads();

    fftA_fwd(xr, xi, twp.x, twp.y);
#pragma unroll
    for (int j = 0; j < 16; ++j) fl[SL(p + 256 * j)] = pk2(xr[j], xi[j]);
    __syncthreads();
    {
        int bb = tid >> 4, o = tid & 15;
#pragma unroll
        for (int j = 0; j < 16; ++j) {
            f16x2 hh = fl[SL(bb * 256 + o + 16 * j)];
            xr[j] = (float)hh.x; xi[j] = (float)hh.y;
        }
        fftB_fwd(xr, xi, two.x, two.y);
#pragma unroll
        for (int j = 0; j < 16; ++j)
            fl[SL(bb * 256 + o + 16 * j)] = pk2(xr[j], xi[j]);
    }
    __syncthreads();
#pragma unroll
    for (int j = 0; j < 16; ++j) {
        f16x2 hh = fl[SL(16 * tid + j)];
        xr[j] = (float)hh.x; xi[j] = (float)hh.y;
    }
    fftC_fwd(xr, xi);

    float sc = 1.0f / (float)NFFT;
    f16x2* outp = Khat + ((size_t)h * D_ + u) * NFFT + 16 * tid;
#pragma unroll
    for (int j = 0; j < 16; ++j) outp[j] = pk2(xr[j] * sc, xi[j] * sc);
}

// ---- dfft body: in-place FFT64 over u of Khat (+1/64, natural-k order) ------
__device__ __forceinline__ void dfft_body(void* smemraw, int blk,
                                          f16x2* __restrict__ Khat,
                                          const float2* __restrict__ tw) {
    float* Xre = (float*)smemraw;
    float* Xim = Xre + 4224;
    int tid = threadIdx.x;
    int f0 = (blk & 63) * 64, h = blk >> 6;
    f16x2* kb = Khat + (size_t)h * D_ * NFFT;
    for (int i = tid; i < 4096; i += 256) {
        int uu = i >> 6, fc = i & 63;
        f16x2 v = kb[(size_t)uu * NFFT + f0 + fc];
        Xre[i] = (float)v.x; Xim[i] = (float)v.y;
    }
    fft64_b(Xre, Xim, tid, tw);
    float sc = 1.0f / 64.0f;
    for (int i = tid; i < 4096; i += 256) {
        int s = i >> 6, fc = i & 63;
        kb[(size_t)drev64(s) * NFFT + f0 + fc] = pk2(Xre[i] * sc, Xim[i] * sc);
    }
}

// ---- vfft body: preb[b][l][e] -> Xv[b][h][k=0..32][l] -----------------------
__device__ __forceinline__ void vfft_body(void* smemraw, int blk,
                                          const bf16* __restrict__ preb,
                                          f16x2* __restrict__ Xv,
                                          const float2* __restrict__ tw) {
    float* Xre = (float*)smemraw;
    float* Xim = Xre + 4224;
    int tid = threadIdx.x;
    int l0 = (blk & 31) * 64, h = (blk >> 5) & 15, b = blk >> 9;
    const bf16* src = preb + ((size_t)(b * L_ + l0)) * E_ + h * 64;
#pragma unroll
    for (int it = 0; it < 2; ++it) {
        int c = tid + it * 256;
        int lc = c >> 3, v8 = (c & 7) * 8;
        bf16x8 xv8 = *(const bf16x8*)(src + (size_t)lc * E_ + v8);
#pragma unroll
        for (int j = 0; j < 8; ++j) {
            Xre[(v8 + j) * 66 + lc] = bfu2f((unsigned short)xv8[j]);
            Xim[(v8 + j) * 66 + lc] = 0.0f;
        }
    }
    fft64_rows<0>(Xre, Xim, tid, tw);
    for (int i = tid; i < 33 * 64; i += 256) {
        int k = i >> 6, lc = i & 63;
        int s = drev64(k);
        Xv[((size_t)(b * H_ + h) * 33 + k) * L_ + l0 + lc] =
            pk2(Xre[s * 66 + lc], Xim[s * 66 + lc]);
    }
}

// ---- merged: GEMM1 (even blocks) | build_khat (odd blocks), interleaved -----
__global__ __launch_bounds__(256) void k_gemm1_khat(const bf16* __restrict__ A,
                                                    const bf16* __restrict__ Wt,
                                                    const float* __restrict__ bias,
                                                    bf16* __restrict__ Cb,
                                                    const float* __restrict__ psfT,
                                                    f16x2* __restrict__ Khat,
                                                    const float2* __restrict__ tw) {
    __shared__ __align__(16) char smem[24576];
    int blk = blockIdx.x;
    if ((blk & 1) == 0)
        gemm_body(smem, blk >> 1, 8, A, Wt, bias, Cb, 1024, E_, E_);
    else
        khat_body(smem, blk >> 1, psfT, Khat, tw);
}

// ---- merged (interleaved, 4096 blocks): blk%4==3 -> GEMM2 | rest dfft/vfft --
__global__ __launch_bounds__(256) void k_gemm2_dfft_vfft(const bf16* __restrict__ A,
                                                         const bf16* __restrict__ Wt,
                                                         const float* __restrict__ bias,
                                                         bf16* __restrict__ Cb,
                                                         f16x2* __restrict__ Khat,
                                                         f16x2* __restrict__ Xv,
                                                         const float2* __restrict__ tw) {
    __shared__ __align__(16) char smem[33792];
    int blk = blockIdx.x;
    if ((blk & 3) == 3) {
        gemm_body(smem, blk >> 2, 8, A, Wt, bias, Cb, 1024, E_, E_);
    } else {
        int rid = blk - (blk >> 2);   // 0..3071 over non-GEMM blocks
        if (rid < 1024)
            dfft_body(smem, rid, Khat, tw);
        else
            vfft_body(smem, rid - 1024, A, Xv, tw);
    }
}

// ---- standalone GEMM3 -------------------------------------------------------
__global__ __launch_bounds__(256) void k_gemm3(const bf16* __restrict__ A,
                                               const bf16* __restrict__ Wt,
                                               const float* __restrict__ bias,
                                               bf16* __restrict__ Cb) {
    __shared__ __align__(16) char smem[24576];
    gemm_body(smem, blockIdx.x, 8, A, Wt, bias, Cb, 1024, E_, E_);
}

// ------ B: fused seq conv per (k,h,b): FFT4096 -> cmul Khat -> IFFT4096 ------
__global__ __launch_bounds__(256) void k_seqconv(f16x2* __restrict__ Xv,
                                                 const f16x2* __restrict__ Khat,
                                                 const float2* __restrict__ tw) {
    __shared__ f16x2 fl[LDSN];
    int k = blockIdx.x, h = blockIdx.y, b = blockIdx.z;
    int tid = threadIdx.x, p = tid;
    f16x2* col = Xv + ((size_t)(b * H_ + h) * 33 + k) * L_;

    float2 twp = tw[p];
    float2 two = tw[(tid & 15) * 16];

    float xr[16], xi[16];
#pragma unroll
    for (int j = 0; j < 16; ++j) {
        if (j < 8) {
            f16x2 z = col[p + 256 * j];
            xr[j] = (float)z.x; xi[j] = (float)z.y;
        } else { xr[j] = 0.0f; xi[j] = 0.0f; }
    }
    fftA_fwd(xr, xi, twp.x, twp.y);
#pragma unroll
    for (int j = 0; j < 16; ++j) fl[SL(p + 256 * j)] = pk2(xr[j], xi[j]);
    __syncthreads();
    {
        int bb = tid >> 4, o = tid & 15;
#pragma unroll
        for (int j = 0; j < 16; ++j) {
            f16x2 hh = fl[SL(bb * 256 + o + 16 * j)];
            xr[j] = (float)hh.x; xi[j] = (float)hh.y;
        }
        fftB_fwd(xr, xi, two.x, two.y);
#pragma unroll
        for (int j = 0; j < 16; ++j)
            fl[SL(bb * 256 + o + 16 * j)] = pk2(xr[j], xi[j]);
    }
    __syncthreads();
    {
        const f16x2* khp = Khat + ((size_t)h * 64 + k) * NFFT + 16 * tid;
        f16x2 kk[16];
#pragma unroll
        for (int j = 0; j < 16; ++j) kk[j] = khp[j];
#pragma unroll
        for (int j = 0; j < 16; ++j) {
            f16x2 hh = fl[SL(16 * tid + j)];
            xr[j] = (float)hh.x; xi[j] = (float)hh.y;
        }
        fftC_fwd(xr, xi);
#pragma unroll
        for (int j = 0; j < 16; ++j) {
            float kr = (float)kk[j].x, ki = (float)kk[j].y;
            float ar = xr[j], ai = xi[j];
            xr[j] = ar * kr - ai * ki;
            xi[j] = ar * ki + ai * kr;
        }
        fftC_inv(xr, xi);
#pragma unroll
        for (int j = 0; j < 16; ++j) fl[SL(16 * tid + j)] = pk2(xr[j], xi[j]);
    }
    __syncthreads();
    {
        int bb = tid >> 4, o = tid & 15;
#pragma unroll
        for (int j = 0; j < 16; ++j) {
            f16x2 hh = fl[SL(bb * 256 + o + 16 * j)];
            xr[j] = (float)hh.x; xi[j] = (float)hh.y;
        }
        fftB_inv(xr, xi, two.x, two.y);
#pragma unroll
        for (int j = 0; j < 16; ++j)
            fl[SL(bb * 256 + o + 16 * j)] = pk2(xr[j], xi[j]);
    }
    __syncthreads();
#pragma unroll
    for (int j = 0; j < 16; ++j) {
        f16x2 hh = fl[SL(p + 256 * j)];
        xr[j] = (float)hh.x; xi[j] = (float)hh.y;
    }
    fftA_inv(xr, xi, twp.x, twp.y);
#pragma unroll
    for (int j = 0; j < 8; ++j)  // only n<2048 needed
        col[p + 256 * j] = pk2(xr[j], xi[j]);
}

// ------ C: inverse v-FFT64 (Hermitian) + GELU -> actb[b][l][e] bf16 ----------
__global__ __launch_bounds__(256) void k_vifft(const f16x2* __restrict__ Xv,
                                               bf16* __restrict__ actb,
                                               const float2* __restrict__ tw) {
    __shared__ float Xre[64 * 66];
    __shared__ float Xim[64 * 66];
    int l0 = blockIdx.x * 64, h = blockIdx.y, b = blockIdx.z;
    int tid = threadIdx.x;
    for (int i = tid; i < 33 * 64; i += 256) {
        int k = i >> 6, lc = i & 63;
        f16x2 z = Xv[((size_t)(b * H_ + h) * 33 + k) * L_ + l0 + lc];
        Xre[k * 66 + lc] = (float)z.x; Xim[k * 66 + lc] = (float)z.y;
    }
    __syncthreads();
    for (int i = tid; i < 31 * 64; i += 256) {
        int k = 33 + (i >> 6), lc = i & 63;
        Xre[k * 66 + lc] =  Xre[(64 - k) * 66 + lc];
        Xim[k * 66 + lc] = -Xim[(64 - k) * 66 + lc];
    }
    fft64_rows<1>(Xre, Xim, tid, tw);
    bf16* dst = actb + ((size_t)(b * L_ + l0)) * E_ + h * 64;
#pragma unroll
    for (int it = 0; it < 2; ++it) {
        int c = tid + it * 256;
        int lc = c >> 3, m8 = (c & 7) * 8;
        unsigned short o[8];
#pragma unroll
        for (int j = 0; j < 8; ++j) {
            float x = Xre[drev64(m8 + j) * 66 + lc];
            float g = 0.5f * x * (1.0f + erff(x * 0.70710678118654752f));
            bf16 bb = __float2bfloat16(g);
            o[j] = *(unsigned short*)&bb;
        }
        *(ushort4*)(dst + (size_t)lc * E_ + m8)     = make_ushort4(o[0], o[1], o[2], o[3]);
        *(ushort4*)(dst + (size_t)lc * E_ + m8 + 4) = make_ushort4(o[4], o[5], o[6], o[7]);
    }
}

// -- fused: row = accbb(bf16) + sparse gather + emb; LayerNorm -> outp (fp32) --
__global__ __launch_bounds__(256) void k_spmm_ln(const int* __restrict__ nnz,
                                                 const int* __restrict__ idxs,
                                                 const float* __restrict__ vals,
                                                 const bf16* __restrict__ P,
                                                 const bf16* __restrict__ accbb,
                                                 const float* __restrict__ emb,
                                                 const float* __restrict__ gamma,
                                                 const float* __restrict__ beta,
                                                 float* __restrict__ outp) {
    __shared__ int sidx[CAP];
    __shared__ float sval[CAP];
    __shared__ float red[256];
    int l = blockIdx.x, b = blockIdx.y, tid = threadIdx.x;
    int n = nnz[l];
    for (int j = tid; j < n; j += 256) {
        sidx[j] = idxs[l * CAP + j];
        sval[j] = vals[l * CAP + j];
    }
    __syncthreads();
    size_t off = (size_t)tid * 4;
    size_t rowbase = ((size_t)(b * L_ + l)) * E_;
    ushort4 a4 = *(const ushort4*)(accbb + rowbase + off);
    float4 e4 = *(const float4*)(emb + rowbase + off);
    float x0 = bfu2f(a4.x) + e4.x;
    float x1 = bfu2f(a4.y) + e4.y;
    float x2 = bfu2f(a4.z) + e4.z;
    float x3 = bfu2f(a4.w) + e4.w;
    const bf16* Pb = P + (size_t)b * L_ * E_;
    for (int j = 0; j < n; ++j) {
        float v = sval[j];
        ushort4 p = *(const ushort4*)(Pb + (size_t)sidx[j] * E_ + off);
        x0 += v * bfu2f(p.x); x1 += v * bfu2f(p.y);
        x2 += v * bfu2f(p.z); x3 += v * bfu2f(p.w);
    }
    red[tid] = x0 + x1 + x2 + x3; __syncthreads();
    for (int o2 = 128; o2 > 0; o2 >>= 1) {
        if (tid < o2) red[tid] += red[tid + o2];
        __syncthreads();
    }
    float mu = red[0] * (1.0f / E_);
    __syncthreads();
    float d0 = x0 - mu, d1 = x1 - mu, d2 = x2 - mu, d3 = x3 - mu;
    red[tid] = d0 * d0 + d1 * d1 + d2 * d2 + d3 * d3; __syncthreads();
    for (int o2 = 128; o2 > 0; o2 >>= 1) {
        if (tid < o2) red[tid] += red[tid + o2];
        __syncthreads();
    }
    float inv = rsqrtf(red[0] * (1.0f / E_) + 1e-12f);
    float4 g4 = *(const float4*)(gamma + off);
    float4 b4 = *(const float4*)(beta + off);
    float4 o4;
    o4.x = d0 * inv * g4.x + b4.x;
    o4.y = d1 * inv * g4.y + b4.y;
    o4.z = d2 * inv * g4.z + b4.z;
    o4.w = d3 * inv * g4.w + b4.w;
    *(float4*)(outp + rowbase + off) = o4;
}

extern "C" void kernel_launch(void* const* d_in, const int* in_sizes, int n_in,
                              void* d_out, int out_size, void* d_ws, size_t ws_size,
                              hipStream_t stream) {
    const float* emb    = (const float*)d_in[0];
    const float* W1     = (const float*)d_in[1];
    const float* b1     = (const float*)d_in[2];
    const float* W2     = (const float*)d_in[3];
    const float* b2     = (const float*)d_in[4];
    const float* psfs   = (const float*)d_in[5];
    const float* W3     = (const float*)d_in[6];
    const float* b3     = (const float*)d_in[7];
    const float* sparse = (const float*)d_in[8];
    const float* gamma  = (const float*)d_in[9];
    const float* beta   = (const float*)d_in[10];
    float* outp = (float*)d_out;

    const size_t BLE  = (size_t)B_ * L_ * E_;
    const size_t EE   = (size_t)E_ * E_;
    const size_t KSZ  = (size_t)H_ * D_ * NFFT;        // f16x2 elems
    const size_t XVSZ = (size_t)B_ * H_ * 33 * L_;     // f16x2 elems

    bf16*   accbb      = (bf16*)d_ws;                  // 16.8 MB
    bf16*   pre_sparse = accbb + BLE;                  // 16.8 MB
    f16x2*  Khat       = (f16x2*)(pre_sparse + BLE);   // 16.8 MB
    f16x2*  Xv         = Khat + KSZ;                   // 17.3 MB
    bf16*   preb       = (bf16*)(Xv + XVSZ);           // 16.8 MB
    bf16*   actb       = preb + BLE;                   // 16.8 MB
    bf16*   W1b        = actb + BLE;                   // 3x 2.1 MB
    bf16*   W2b        = W1b + EE;
    bf16*   W3b        = W2b + EE;
    float2* twd        = (float2*)(W3b + EE);          // 32 KB
    int*    s_nnz      = (int*)(twd + NFFT);           // dedicated region (~2MB)
    int*    s_idx      = s_nnz + L_;
    float*  s_val      = (float*)(s_idx + (size_t)L_ * CAP);
    // psfT overlays Xv (dead before vfft writes Xv)
    float*  psfT       = (float*)Xv;

    // prologue: twiddle | emb->bf16 | W1..3->bf16 | psf transpose | sparse lists
    k_prologue<<<NB_TW + NB_CVT + NB_CVTW + NB_TF + NB_SP, 256, 0, stream>>>(
        emb, W1, W2, W3, psfs, sparse, twd, actb, W1b, psfT, s_nnz, s_idx, s_val);

    // merged (interleaved): preb = bf16(emb @ W1^T + b1)  ||  build_khat
    k_gemm1_khat<<<2048, 256, 0, stream>>>(actb, W1b, b1, preb, psfT, Khat, twd);

    // merged (interleaved): pre_sparse = GEMM2 || dfft(Khat) || vfft(preb)
    k_gemm2_dfft_vfft<<<4096, 256, 0, stream>>>(preb, W2b, b2, pre_sparse, Khat, Xv, twd);

    // fused per-(k,h,b) seq conv (in place)
    k_seqconv<<<dim3(33, H_, B_), 256, 0, stream>>>(Xv, Khat, twd);

    // inverse v-FFT + GELU -> actb
    k_vifft<<<dim3(L_ / 64, H_, B_), 256, 0, stream>>>(Xv, actb, twd);

    // accbb = bf16(conv @ W3^T + b3)
    k_gemm3<<<1024, 256, 0, stream>>>(actb, W3b, b3, accbb);

    // fused: out = LayerNorm(accbb + tril(sparse)@pre_sparse + emb)
    k_spmm_ln<<<dim3(L_, B_), 256, 0, stream>>>(
        s_nnz, s_idx, s_val, pre_sparse, accbb, emb, gamma, beta, outp);
}

// Round 21
// 196.804 us; speedup vs baseline: 1.1813x; 1.1813x over previous
//
#include <hip/hip_runtime.h>
#include <hip/hip_bf16.h>
#include <hip/hip_fp16.h>
#include <math.h>

#define B_ 4
#define L_ 2048
#define E_ 1024
#define H_ 16
#define D_ 64
#define NFFT 4096
#define CAP 128

typedef __hip_bfloat16 bf16;
typedef __attribute__((ext_vector_type(8))) short bf16x8;
typedef __attribute__((ext_vector_type(4))) float f32x4;
typedef __attribute__((ext_vector_type(2))) __fp16 f16x2;

typedef __attribute__((address_space(1))) const unsigned int gas_u32;
typedef __attribute__((address_space(3))) unsigned int las_u32;

__device__ __forceinline__ void gload_lds16(const void* g, void* l) {
    __builtin_amdgcn_global_load_lds((gas_u32*)g, (las_u32*)l, 16, 0, 0);
}

// padded LDS slot: +1 per 16 (<=2-way conflicts for all 3 phase patterns)
#define SL(i) ((i) + ((i) >> 4))
#define LDSN (NFFT + NFFT / 16)   // 4352

__device__ __forceinline__ float bfu2f(unsigned short u) {
    return __uint_as_float(((unsigned)u) << 16);
}
__device__ __forceinline__ f16x2 pk2(float a, float b) {
    return __builtin_amdgcn_cvt_pkrtz(a, b);
}

// base-4 3-digit reversal (involution)
__device__ __forceinline__ int drev64(int k) {
    return ((k & 3) << 4) | (k & 12) | ((k >> 4) & 3);
}

// stage-1 constants: C[j] = tw[256*j] = exp(-i*pi*j/8)
#define C1R 0.923879532511287f
#define C1I -0.382683432365090f
#define C2R 0.707106781186548f
#define C2I -0.707106781186548f
#define C3R 0.382683432365090f
#define C3I -0.923879532511287f

// ------- register radix-4 butterflies; w2=w1^2, w3=w1^3 derived in-reg -------
__device__ __forceinline__ void r4dif_w(float& x0r, float& x0i, float& x1r, float& x1i,
                                        float& x2r, float& x2i, float& x3r, float& x3i,
                                        float w1r, float w1i) {
    float a0r = x0r + x2r, a0i = x0i + x2i, a1r = x0r - x2r, a1i = x0i - x2i;
    float a2r = x1r + x3r, a2i = x1i + x3i, a3r = x1r - x3r, a3i = x1i - x3i;
    float y0r = a0r + a2r, y0i = a0i + a2i, y2r = a0r - a2r, y2i = a0i - a2i;
    float y1r = a1r + a3i, y1i = a1i - a3r, y3r = a1r - a3i, y3i = a1i + a3r;
    float w2r = w1r * w1r - w1i * w1i, w2i = 2.0f * w1r * w1i;
    float w3r = w2r * w1r - w2i * w1i, w3i = w2r * w1i + w2i * w1r;
    x0r = y0r; x0i = y0i;
    x1r = y1r * w1r - y1i * w1i; x1i = y1r * w1i + y1i * w1r;
    x2r = y2r * w2r - y2i * w2i; x2i = y2r * w2i + y2i * w2r;
    x3r = y3r * w3r - y3i * w3i; x3i = y3r * w3i + y3i * w3r;
}
__device__ __forceinline__ void r4dif_nt(float& x0r, float& x0i, float& x1r, float& x1i,
                                         float& x2r, float& x2i, float& x3r, float& x3i) {
    float a0r = x0r + x2r, a0i = x0i + x2i, a1r = x0r - x2r, a1i = x0i - x2i;
    float a2r = x1r + x3r, a2i = x1i + x3i, a3r = x1r - x3r, a3i = x1i - x3i;
    x0r = a0r + a2r; x0i = a0i + a2i;
    x2r = a0r - a2r; x2i = a0i - a2i;
    float y1r = a1r + a3i, y1i = a1i - a3r, y3r = a1r - a3i, y3i = a1i + a3r;
    x1r = y1r; x1i = y1i; x3r = y3r; x3i = y3i;
}
__device__ __forceinline__ void r4dit_w(float& x0r, float& x0i, float& x1r, float& x1i,
                                        float& x2r, float& x2i, float& x3r, float& x3i,
                                        float w1r, float w1i) {
    float w2r = w1r * w1r - w1i * w1i, w2i = 2.0f * w1r * w1i;
    float w3r = w2r * w1r - w2i * w1i, w3i = w2r * w1i + w2i * w1r;
    float z1r = x1r * w1r + x1i * w1i, z1i = x1i * w1r - x1r * w1i;
    float z2r = x2r * w2r + x2i * w2i, z2i = x2i * w2r - x2r * w2i;
    float z3r = x3r * w3r + x3i * w3i, z3i = x3i * w3r - x3r * w3i;
    float b0r = x0r + z2r, b0i = x0i + z2i, b1r = x0r - z2r, b1i = x0i - z2i;
    float b2r = z1r + z3r, b2i = z1i + z3i, b3r = z1r - z3r, b3i = z1i - z3i;
    x0r = b0r + b2r; x0i = b0i + b2i;
    x2r = b0r - b2r; x2i = b0i - b2i;
    x1r = b1r - b3i; x1i = b1i + b3r;
    x3r = b1r + b3i; x3i = b1i - b3r;
}
__device__ __forceinline__ void r4dit_nt(float& x0r, float& x0i, float& x1r, float& x1i,
                                         float& x2r, float& x2i, float& x3r, float& x3i) {
    float b0r = x0r + x2r, b0i = x0i + x2i, b1r = x0r - x2r, b1i = x0i - x2i;
    float b2r = x1r + x3r, b2i = x1i + x3i, b3r = x1r - x3r, b3i = x1i - x3i;
    x0r = b0r + b2r; x0i = b0i + b2i;
    x2r = b0r - b2r; x2i = b0i - b2i;
    x1r = b1r - b3i; x1i = b1i + b3r;
    x3r = b1r + b3i; x3i = b1i - b3r;
}

// ---- phase A (stages 0,1): thread p owns X[j]=a[p+256j]; wp = tw[p] ---------
__device__ __forceinline__ void fftA_fwd(float* xr, float* xi, float wpr, float wpi) {
    r4dif_w(xr[0], xi[0], xr[4], xi[4], xr[8], xi[8], xr[12], xi[12], wpr, wpi);
    r4dif_w(xr[1], xi[1], xr[5], xi[5], xr[9], xi[9], xr[13], xi[13],
            wpr * C1R - wpi * C1I, wpr * C1I + wpi * C1R);
    r4dif_w(xr[2], xi[2], xr[6], xi[6], xr[10], xi[10], xr[14], xi[14],
            wpr * C2R - wpi * C2I, wpr * C2I + wpi * C2R);
    r4dif_w(xr[3], xi[3], xr[7], xi[7], xr[11], xi[11], xr[15], xi[15],
            wpr * C3R - wpi * C3I, wpr * C3I + wpi * C3R);
    float s2r = wpr * wpr - wpi * wpi, s2i = 2.0f * wpr * wpi;
    float w4r = s2r * s2r - s2i * s2i, w4i = 2.0f * s2r * s2i;
#pragma unroll
    for (int g = 0; g < 4; ++g)
        r4dif_w(xr[4 * g], xi[4 * g], xr[4 * g + 1], xi[4 * g + 1], xr[4 * g + 2],
                xi[4 * g + 2], xr[4 * g + 3], xi[4 * g + 3], w4r, w4i);
}
__device__ __forceinline__ void fftA_inv(float* xr, float* xi, float wpr, float wpi) {
    float s2r = wpr * wpr - wpi * wpi, s2i = 2.0f * wpr * wpi;
    float w4r = s2r * s2r - s2i * s2i, w4i = 2.0f * s2r * s2i;
#pragma unroll
    for (int g = 0; g < 4; ++g)
        r4dit_w(xr[4 * g], xi[4 * g], xr[4 * g + 1], xi[4 * g + 1], xr[4 * g + 2],
                xi[4 * g + 2], xr[4 * g + 3], xi[4 * g + 3], w4r, w4i);
    r4dit_w(xr[0], xi[0], xr[4], xi[4], xr[8], xi[8], xr[12], xi[12], wpr, wpi);
    r4dit_w(xr[1], xi[1], xr[5], xi[5], xr[9], xi[9], xr[13], xi[13],
            wpr * C1R - wpi * C1I, wpr * C1I + wpi * C1R);
    r4dit_w(xr[2], xi[2], xr[6], xi[6], xr[10], xi[10], xr[14], xi[14],
            wpr * C2R - wpi * C2I, wpr * C2I + wpi * C2R);
    r4dit_w(xr[3], xi[3], xr[7], xi[7], xr[11], xi[11], xr[15], xi[15],
            wpr * C3R - wpi * C3I, wpr * C3I + wpi * C3R);
}
// ---- phase B (stages 2,3): thread (b,o) owns X[j]=a[b*256+o+16j]; wo=tw[16o]
__device__ __forceinline__ void fftB_fwd(float* xr, float* xi, float wor, float woi) {
    r4dif_w(xr[0], xi[0], xr[4], xi[4], xr[8], xi[8], xr[12], xi[12], wor, woi);
    r4dif_w(xr[1], xi[1], xr[5], xi[5], xr[9], xi[9], xr[13], xi[13],
            wor * C1R - woi * C1I, wor * C1I + woi * C1R);
    r4dif_w(xr[2], xi[2], xr[6], xi[6], xr[10], xi[10], xr[14], xi[14],
            wor * C2R - woi * C2I, wor * C2I + woi * C2R);
    r4dif_w(xr[3], xi[3], xr[7], xi[7], xr[11], xi[11], xr[15], xi[15],
            wor * C3R - woi * C3I, wor * C3I + woi * C3R);
    float s2r = wor * wor - woi * woi, s2i = 2.0f * wor * woi;
    float w4r = s2r * s2r - s2i * s2i, w4i = 2.0f * s2r * s2i;
#pragma unroll
    for (int g = 0; g < 4; ++g)
        r4dif_w(xr[4 * g], xi[4 * g], xr[4 * g + 1], xi[4 * g + 1], xr[4 * g + 2],
                xi[4 * g + 2], xr[4 * g + 3], xi[4 * g + 3], w4r, w4i);
}
__device__ __forceinline__ void fftB_inv(float* xr, float* xi, float wor, float woi) {
    float s2r = wor * wor - woi * woi, s2i = 2.0f * wor * woi;
    float w4r = s2r * s2r - s2i * s2i, w4i = 2.0f * s2r * s2i;
#pragma unroll
    for (int g = 0; g < 4; ++g)
        r4dit_w(xr[4 * g], xi[4 * g], xr[4 * g + 1], xi[4 * g + 1], xr[4 * g + 2],
                xi[4 * g + 2], xr[4 * g + 3], xi[4 * g + 3], w4r, w4i);
    r4dit_w(xr[0], xi[0], xr[4], xi[4], xr[8], xi[8], xr[12], xi[12], wor, woi);
    r4dit_w(xr[1], xi[1], xr[5], xi[5], xr[9], xi[9], xr[13], xi[13],
            wor * C1R - woi * C1I, wor * C1I + woi * C1R);
    r4dit_w(xr[2], xi[2], xr[6], xi[6], xr[10], xi[10], xr[14], xi[14],
            wor * C2R - woi * C2I, wor * C2I + woi * C2R);
    r4dit_w(xr[3], xi[3], xr[7], xi[7], xr[11], xi[11], xr[15], xi[15],
            wor * C3R - woi * C3I, wor * C3I + woi * C3R);
}
// ---- phase C (stages 4,5): thread t owns X[j]=a[16t+j]; constant twiddles ---
__device__ __forceinline__ void fftC_fwd(float* xr, float* xi) {
    r4dif_w(xr[0], xi[0], xr[4], xi[4], xr[8], xi[8], xr[12], xi[12], 1.0f, 0.0f);
    r4dif_w(xr[1], xi[1], xr[5], xi[5], xr[9], xi[9], xr[13], xi[13], C1R, C1I);
    r4dif_w(xr[2], xi[2], xr[6], xi[6], xr[10], xi[10], xr[14], xi[14], C2R, C2I);
    r4dif_w(xr[3], xi[3], xr[7], xi[7], xr[11], xi[11], xr[15], xi[15], C3R, C3I);
#pragma unroll
    for (int g = 0; g < 4; ++g)
        r4dif_nt(xr[4 * g], xi[4 * g], xr[4 * g + 1], xi[4 * g + 1], xr[4 * g + 2],
                 xi[4 * g + 2], xr[4 * g + 3], xi[4 * g + 3]);
}
__device__ __forceinline__ void fftC_inv(float* xr, float* xi) {
#pragma unroll
    for (int g = 0; g < 4; ++g)
        r4dit_nt(xr[4 * g], xi[4 * g], xr[4 * g + 1], xi[4 * g + 1], xr[4 * g + 2],
                 xi[4 * g + 2], xr[4 * g + 3], xi[4 * g + 3]);
    r4dit_w(xr[0], xi[0], xr[4], xi[4], xr[8], xi[8], xr[12], xi[12], 1.0f, 0.0f);
    r4dit_w(xr[1], xi[1], xr[5], xi[5], xr[9], xi[9], xr[13], xi[13], C1R, C1I);
    r4dit_w(xr[2], xi[2], xr[6], xi[6], xr[10], xi[10], xr[14], xi[14], C2R, C2I);
    r4dit_w(xr[3], xi[3], xr[7], xi[7], xr[11], xi[11], xr[15], xi[15], C3R, C3I);
}

// ---- batched 64-pt radix-4 over rows, LDS layout idx = row*66 + col ---------
template <int CONJ>
__device__ inline void fft64_rows(float* xr, float* xi, int tid,
                                  const float2* __restrict__ tw) {
    for (int st = 0; st < 3; ++st) {
        int q = 1 << (4 - 2 * st);
        __syncthreads();
        for (int it = 0; it < 4; ++it) {
            int w = tid + (it << 8);
            int lc = w & 63, bc = w >> 6;
            int p = bc & (q - 1);
            int basev = ((bc & ~(q - 1)) << 2) | p;
            int i0 = basev * 66 + lc, i1 = i0 + q * 66, i2 = i1 + q * 66, i3 = i2 + q * 66;
            float x0r = xr[i0], x0i = xi[i0], x1r = xr[i1], x1i = xi[i1];
            float x2r = xr[i2], x2i = xi[i2], x3r = xr[i3], x3i = xi[i3];
            float a0r = x0r + x2r, a0i = x0i + x2i;
            float a1r = x0r - x2r, a1i = x0i - x2i;
            float a2r = x1r + x3r, a2i = x1i + x3i;
            float a3r = x1r - x3r, a3i = x1i - x3i;
            float y0r = a0r + a2r, y0i = a0i + a2i;
            float y2r = a0r - a2r, y2i = a0i - a2i;
            float y1r, y1i, y3r, y3i;
            if (!CONJ) {
                y1r = a1r + a3i; y1i = a1i - a3r;
                y3r = a1r - a3i; y3i = a1i + a3r;
            } else {
                y1r = a1r - a3i; y1i = a1i + a3r;
                y3r = a1r + a3i; y3i = a1i - a3r;
            }
            int e = (p << (2 * st)) * 64;
            float2 w1 = tw[e];
            float w1x = w1.x, w1y = CONJ ? -w1.y : w1.y;
            float w2x = w1x * w1x - w1y * w1y, w2y = 2.0f * w1x * w1y;
            float w3x = w2x * w1x - w2y * w1y, w3y = w2x * w1y + w2y * w1x;
            xr[i0] = y0r; xi[i0] = y0i;
            xr[i1] = y1r * w1x - y1i * w1y; xi[i1] = y1r * w1y + y1i * w1x;
            xr[i2] = y2r * w2x - y2i * w2y; xi[i2] = y2r * w2y + y2i * w2x;
            xr[i3] = y3r * w3x - y3i * w3y; xi[i3] = y3r * w3y + y3i * w3x;
        }
    }
    __syncthreads();
}

// ------- batched 64-pt radix-4 FFT over rows in [row*64+col] layout ----------
__device__ inline void fft64_b(float* xr, float* xi, int tid,
                               const float2* __restrict__ tw) {
    for (int st = 0; st < 3; ++st) {
        int q = 1 << (4 - 2 * st);
        __syncthreads();
        for (int it = 0; it < 4; ++it) {
            int b = tid + (it << 8);
            int fc = b & 63;
            int bc = b >> 6;
            int p = bc & (q - 1);
            int basev = ((bc & ~(q - 1)) << 2) | p;
            int i0 = basev * 64 + fc, i1 = i0 + q * 64, i2 = i1 + q * 64, i3 = i2 + q * 64;
            float x0r = xr[i0], x0i = xi[i0], x1r = xr[i1], x1i = xi[i1];
            float x2r = xr[i2], x2i = xi[i2], x3r = xr[i3], x3i = xi[i3];
            float a0r = x0r + x2r, a0i = x0i + x2i;
            float a1r = x0r - x2r, a1i = x0i - x2i;
            float a2r = x1r + x3r, a2i = x1i + x3i;
            float a3r = x1r - x3r, a3i = x1i - x3i;
            float y0r = a0r + a2r, y0i = a0i + a2i;
            float y2r = a0r - a2r, y2i = a0i - a2i;
            float y1r = a1r + a3i, y1i = a1i - a3r;
            float y3r = a1r - a3i, y3i = a1i + a3r;
            int e = (p << (2 * st)) * 64;
            float2 w1 = tw[e];
            float w2x = w1.x * w1.x - w1.y * w1.y, w2y = 2.0f * w1.x * w1.y;
            float w3x = w2x * w1.x - w2y * w1.y, w3y = w2x * w1.y + w2y * w1.x;
            xr[i0] = y0r; xi[i0] = y0i;
            xr[i1] = y1r * w1.x - y1i * w1.y; xi[i1] = y1r * w1.y + y1i * w1.x;
            xr[i2] = y2r * w2x - y2i * w2y; xi[i2] = y2r * w2y + y2i * w2x;
            xr[i3] = y3r * w3x - y3i * w3y; xi[i3] = y3r * w3y + y3i * w3x;
        }
    }
    __syncthreads();
}

// ---- merged prologue: twiddle | emb cvt | W cvt | psf transpose | sparse ----
#define NB_TW 16
#define NB_CVT 8192
#define NB_CVTW 3072
#define NB_TF 512
#define NB_SP 2048
__global__ __launch_bounds__(256) void k_prologue(const float* __restrict__ emb,
                                                  const float* __restrict__ W1,
                                                  const float* __restrict__ W2,
                                                  const float* __restrict__ W3,
                                                  const float* __restrict__ psfs,
                                                  const float* __restrict__ Sp,
                                                  float2* __restrict__ tw,
                                                  bf16* __restrict__ embb,
                                                  bf16* __restrict__ Wb,
                                                  float* __restrict__ psfT,
                                                  int* __restrict__ nnz,
                                                  int* __restrict__ idxs,
                                                  float* __restrict__ vals) {
    __shared__ float tile[64][65];
    __shared__ int cnt;
    int tid = threadIdx.x;
    int blk = blockIdx.x;
    if (blk < NB_TW) {
        int k = blk * 256 + tid;
        float ang = -(float)k * (float)(M_PI / 2048.0);
        tw[k] = make_float2(cosf(ang), sinf(ang));
        return;
    }
    blk -= NB_TW;
    if (blk < NB_CVT) {
        int i = (blk * 256 + tid) * 4;
        float4 v = *(const float4*)(emb + i);
        bf16 tmp[4];
        tmp[0] = __float2bfloat16(v.x); tmp[1] = __float2bfloat16(v.y);
        tmp[2] = __float2bfloat16(v.z); tmp[3] = __float2bfloat16(v.w);
        *(ushort4*)(embb + i) = *(ushort4*)tmp;
        return;
    }
    blk -= NB_CVT;
    if (blk < NB_CVTW) {
        int w = blk >> 10;
        const float* src = (w == 0) ? W1 : (w == 1) ? W2 : W3;
        int i = ((blk & 1023) * 256 + tid) * 4;
        float4 v = *(const float4*)(src + i);
        bf16 tmp[4];
        tmp[0] = __float2bfloat16(v.x); tmp[1] = __float2bfloat16(v.y);
        tmp[2] = __float2bfloat16(v.z); tmp[3] = __float2bfloat16(v.w);
        *(ushort4*)(Wb + (size_t)w * E_ * E_ + i) = *(ushort4*)tmp;
        return;
    }
    blk -= NB_CVTW;
    if (blk < NB_TF) {
        int z = blk >> 5;
        int r0 = (blk & 31) * 64;
        const float* in = psfs + (size_t)z * (2 * L_ - 1) * D_;
        float* out = psfT + (size_t)z * D_ * L_;
        int tx4 = (tid & 15) * 4, ty = tid >> 4;
#pragma unroll
        for (int k = 0; k < 4; ++k) {
            int r = ty + 16 * k;
            float4 v = *(const float4*)&in[(size_t)(r0 + r) * D_ + tx4];
            tile[r][tx4 + 0] = v.x; tile[r][tx4 + 1] = v.y;
            tile[r][tx4 + 2] = v.z; tile[r][tx4 + 3] = v.w;
        }
        __syncthreads();
#pragma unroll
        for (int k = 0; k < 4; ++k) {
            int c = ty + 16 * k;
            float4 w;
            w.x = tile[tx4 + 0][c]; w.y = tile[tx4 + 1][c];
            w.z = tile[tx4 + 2][c]; w.w = tile[tx4 + 3][c];
            *(float4*)&out[(size_t)c * L_ + r0 + tx4] = w;
        }
        return;
    }
    blk -= NB_TF;
    {
        int l = blk;
        if (tid == 0) cnt = 0;
        __syncthreads();
        const float* row = Sp + (size_t)l * L_;
        for (int s = tid; s <= l; s += 256) {
            float v = row[s];
            if (v != 0.0f) {
                int slot = atomicAdd(&cnt, 1);
                if (slot < CAP) { idxs[l * CAP + slot] = s; vals[l * CAP + slot] = v; }
            }
        }
        __syncthreads();
        if (tid == 0) nnz[l] = min(cnt, CAP);
    }
}

// ---- GEMM body (64x128 tile, BK=64, swizzled LDS, XCD swizzle), bf16 out ----
__device__ __forceinline__ void gemm_body(void* smemraw, int flat, int nwgx,
                                          const bf16* __restrict__ A,
                                          const bf16* __restrict__ Wt,
                                          const float* __restrict__ bias,
                                          bf16* __restrict__ Cb,
                                          int nwg, int N, int K) {
    bf16* As = (bf16*)smemraw;        // 64*64
    bf16* Bs = As + 64 * 64;          // 128*64
    int tid = threadIdx.x;
    int lane = tid & 63, w = tid >> 6;
    int wr = w >> 1, wc = w & 1;

    int cpx = nwg >> 3;
    int swz = (flat & 7) * cpx + (flat >> 3);
    int bx = (swz % nwgx) * 128;
    int by = (swz / nwgx) * 64;

    f32x4 zz = {0.0f, 0.0f, 0.0f, 0.0f};
    f32x4 acc[2][4];
#pragma unroll
    for (int m = 0; m < 2; ++m)
#pragma unroll
        for (int n = 0; n < 4; ++n) acc[m][n] = zz;

    int koff = (lane >> 4) * 8;
    int rsub = lane & 15;

    for (int k0 = 0; k0 < K; k0 += 64) {
#pragma unroll
        for (int i = 0; i < 2; ++i) {
            int c = tid + i * 256;
            int row = c >> 3;
            int kb = (c & 7) * 8;
            int kbs = kb ^ ((row & 7) << 3);
            gload_lds16(A + (size_t)(by + row) * K + k0 + kbs, &As[c * 8]);
        }
#pragma unroll
        for (int i = 0; i < 4; ++i) {
            int c = tid + i * 256;
            int row = c >> 3;
            int kb = (c & 7) * 8;
            int kbs = kb ^ ((row & 7) << 3);
            gload_lds16(Wt + (size_t)(bx + row) * K + k0 + kbs, &Bs[c * 8]);
        }
        __syncthreads();
#pragma unroll
        for (int half = 0; half < 2; ++half) {
            int ko = koff + half * 32;
            bf16x8 af[2], bfv[4];
#pragma unroll
            for (int m = 0; m < 2; ++m) {
                int R = wr * 32 + m * 16 + rsub;
                af[m] = *(const bf16x8*)&As[R * 64 + (ko ^ ((R & 7) << 3))];
            }
#pragma unroll
            for (int n = 0; n < 4; ++n) {
                int R = wc * 64 + n * 16 + rsub;
                bfv[n] = *(const bf16x8*)&Bs[R * 64 + (ko ^ ((R & 7) << 3))];
            }
#pragma unroll
            for (int m = 0; m < 2; ++m)
#pragma unroll
                for (int n = 0; n < 4; ++n)
                    acc[m][n] = __builtin_amdgcn_mfma_f32_16x16x32_bf16(af[m], bfv[n], acc[m][n], 0, 0, 0);
        }
        __syncthreads();
    }

    int cq = (lane >> 4) * 4;
    int cr = lane & 15;
#pragma unroll
    for (int m = 0; m < 2; ++m) {
        int row0 = by + wr * 32 + m * 16 + cq;
#pragma unroll
        for (int n = 0; n < 4; ++n) {
            int col = bx + wc * 64 + n * 16 + cr;
            float bv = bias[col];
#pragma unroll
            for (int j = 0; j < 4; ++j) {
                float v = acc[m][n][j] + bv;
                Cb[(size_t)(row0 + j) * N + col] = __float2bfloat16(v);
            }
        }
    }
}

// ---- build_khat body: PSF softmax + FULL K4096 + fwd FFT --------------------
__device__ __forceinline__ void khat_body(void* smemraw, int blk,
                                          const float* __restrict__ psfT,
                                          f16x2* __restrict__ Khat,
                                          const float2* __restrict__ tw) {
    f16x2* fl = (f16x2*)smemraw;
    float* red = (float*)(fl + LDSN);
    int u = blk & 63, h = blk >> 6;
    int tid = threadIdx.x;
    const float* col = psfT + ((size_t)(h * D_ + u)) * L_;
    int p = tid;

    float2 twp = tw[p];
    float2 two = tw[(tid & 15) * 16];

    float v[8];
#pragma unroll
    for (int j = 0; j < 8; ++j) v[j] = col[p + 256 * j];

    float lm = v[0];
#pragma unroll
    for (int j = 1; j < 8; ++j) lm = fmaxf(lm, v[j]);
    red[tid] = lm; __syncthreads();
    for (int off = 128; off > 0; off >>= 1) {
        if (tid < off) red[tid] = fmaxf(red[tid], red[tid + off]);
        __syncthreads();
    }
    float M = fmaxf(red[0], 0.0f);
    __syncthreads();

    float e[8];
    float ls = 0.0f;
#pragma unroll
    for (int j = 0; j < 8; ++j) { e[j] = expf(v[j] - M); ls += e[j]; }
    red[tid] = ls; __syncthreads();
    for (int off = 128; off > 0; off >>= 1) {
        if (tid < off) red[tid] += red[tid + off];
        __syncthreads();
    }
    float Z = red[0] + (float)(L_ - 1) * expf(-M);
    float invZ = 1.0f / Z;
    float cval = expf(-M) * invZ;

    float xr[16], xi[16];
#pragma unroll
    for (int j = 0; j < 16; ++j) {
        int i = p + 256 * j;
        xr[j] = (j < 8) ? e[j] * invZ : ((i == 2048) ? 0.0f : cval);
        xi[j] = 0.0f;
    }
    __syncthreads();

    fftA_fwd(xr, xi, twp.x, twp.y);
#pragma unroll
    for (int j = 0; j < 16; ++j) fl[SL(p + 256 * j)] = pk2(xr[j], xi[j]);
    __syncthreads();
    {
        int bb = tid >> 4, o = tid & 15;
#pragma unroll
        for (int j = 0; j < 16; ++j) {
            f16x2 hh = fl[SL(bb * 256 + o + 16 * j)];
            xr[j] = (float)hh.x; xi[j] = (float)hh.y;
        }
        fftB_fwd(xr, xi, two.x, two.y);
#pragma unroll
        for (int j = 0; j < 16; ++j)
            fl[SL(bb * 256 + o + 16 * j)] = pk2(xr[j], xi[j]);
    }
    __syncthreads();
#pragma unroll
    for (int j = 0; j < 16; ++j) {
        f16x2 hh = fl[SL(16 * tid + j)];
        xr[j] = (float)hh.x; xi[j] = (float)hh.y;
    }
    fftC_fwd(xr, xi);

    float sc = 1.0f / (float)NFFT;
    f16x2* outp = Khat + ((size_t)h * D_ + u) * NFFT + 16 * tid;
#pragma unroll
    for (int j = 0; j < 16; ++j) outp[j] = pk2(xr[j] * sc, xi[j] * sc);
}

// ---- dfft body: in-place FFT64 over u of Khat (+1/64, natural-k order) ------
__device__ __forceinline__ void dfft_body(void* smemraw, int blk,
                                          f16x2* __restrict__ Khat,
                                          const float2* __restrict__ tw) {
    float* Xre = (float*)smemraw;
    float* Xim = Xre + 4224;
    int tid = threadIdx.x;
    int f0 = (blk & 63) * 64, h = blk >> 6;
    f16x2* kb = Khat + (size_t)h * D_ * NFFT;
    for (int i = tid; i < 4096; i += 256) {
        int uu = i >> 6, fc = i & 63;
        f16x2 v = kb[(size_t)uu * NFFT + f0 + fc];
        Xre[i] = (float)v.x; Xim[i] = (float)v.y;
    }
    fft64_b(Xre, Xim, tid, tw);
    float sc = 1.0f / 64.0f;
    for (int i = tid; i < 4096; i += 256) {
        int s = i >> 6, fc = i & 63;
        kb[(size_t)drev64(s) * NFFT + f0 + fc] = pk2(Xre[i] * sc, Xim[i] * sc);
    }
}

// ---- vfft body: preb[b][l][e] -> Xv[b][h][k=0..32][l] -----------------------
__device__ __forceinline__ void vfft_body(void* smemraw, int blk,
                                          const bf16* __restrict__ preb,
                                          f16x2* __restrict__ Xv,
                                          const float2* __restrict__ tw) {
    float* Xre = (float*)smemraw;
    float* Xim = Xre + 4224;
    int tid = threadIdx.x;
    int l0 = (blk & 31) * 64, h = (blk >> 5) & 15, b = blk >> 9;
    const bf16* src = preb + ((size_t)(b * L_ + l0)) * E_ + h * 64;
#pragma unroll
    for (int it = 0; it < 2; ++it) {
        int c = tid + it * 256;
        int lc = c >> 3, v8 = (c & 7) * 8;
        bf16x8 xv8 = *(const bf16x8*)(src + (size_t)lc * E_ + v8);
#pragma unroll
        for (int j = 0; j < 8; ++j) {
            Xre[(v8 + j) * 66 + lc] = bfu2f((unsigned short)xv8[j]);
            Xim[(v8 + j) * 66 + lc] = 0.0f;
        }
    }
    fft64_rows<0>(Xre, Xim, tid, tw);
    for (int i = tid; i < 33 * 64; i += 256) {
        int k = i >> 6, lc = i & 63;
        int s = drev64(k);
        Xv[((size_t)(b * H_ + h) * 33 + k) * L_ + l0 + lc] =
            pk2(Xre[s * 66 + lc], Xim[s * 66 + lc]);
    }
}

// ---- merged: [0,1024) GEMM1 | [1024,2048) build_khat ------------------------
__global__ __launch_bounds__(256) void k_gemm1_khat(const bf16* __restrict__ A,
                                                    const bf16* __restrict__ Wt,
                                                    const float* __restrict__ bias,
                                                    bf16* __restrict__ Cb,
                                                    const float* __restrict__ psfT,
                                                    f16x2* __restrict__ Khat,
                                                    const float2* __restrict__ tw) {
    __shared__ __align__(16) char smem[24576];
    int blk = blockIdx.x;
    if (blk < 1024)
        gemm_body(smem, blk, 8, A, Wt, bias, Cb, 1024, E_, E_);
    else
        khat_body(smem, blk - 1024, psfT, Khat, tw);
}

// ---- merged: [0,1024) GEMM2 | [1024,2048) dfft | [2048,4096) vfft -----------
__global__ __launch_bounds__(256) void k_gemm2_dfft_vfft(const bf16* __restrict__ A,
                                                         const bf16* __restrict__ Wt,
                                                         const float* __restrict__ bias,
                                                         bf16* __restrict__ Cb,
                                                         f16x2* __restrict__ Khat,
                                                         f16x2* __restrict__ Xv,
                                                         const float2* __restrict__ tw) {
    __shared__ __align__(16) char smem[33792];
    int blk = blockIdx.x;
    if (blk < 1024)
        gemm_body(smem, blk, 8, A, Wt, bias, Cb, 1024, E_, E_);
    else if (blk < 2048)
        dfft_body(smem, blk - 1024, Khat, tw);
    else
        vfft_body(smem, blk - 2048, A, Xv, tw);
}

// ---- standalone GEMM3 -------------------------------------------------------
__global__ __launch_bounds__(256) void k_gemm3(const bf16* __restrict__ A,
                                               const bf16* __restrict__ Wt,
                                               const float* __restrict__ bias,
                                               bf16* __restrict__ Cb) {
    __shared__ __align__(16) char smem[24576];
    gemm_body(smem, blockIdx.x, 8, A, Wt, bias, Cb, 1024, E_, E_);
}

// ------ B: fused seq conv per (k,h,b): FFT4096 -> cmul Khat -> IFFT4096 ------
__global__ __launch_bounds__(256) void k_seqconv(f16x2* __restrict__ Xv,
                                                 const f16x2* __restrict__ Khat,
                                                 const float2* __restrict__ tw) {
    __shared__ f16x2 fl[LDSN];
    int k = blockIdx.x, h = blockIdx.y, b = blockIdx.z;
    int tid = threadIdx.x, p = tid;
    f16x2* col = Xv + ((size_t)(b * H_ + h) * 33 + k) * L_;

    float2 twp = tw[p];
    float2 two = tw[(tid & 15) * 16];

    float xr[16], xi[16];
#pragma unroll
    for (int j = 0; j < 16; ++j) {
        if (j < 8) {
            f16x2 z = col[p + 256 * j];
            xr[j] = (float)z.x; xi[j] = (float)z.y;
        } else { xr[j] = 0.0f; xi[j] = 0.0f; }
    }
    fftA_fwd(xr, xi, twp.x, twp.y);
#pragma unroll
    for (int j = 0; j < 16; ++j) fl[SL(p + 256 * j)] = pk2(xr[j], xi[j]);
    __syncthreads();
    {
        int bb = tid >> 4, o = tid & 15;
#pragma unroll
        for (int j = 0; j < 16; ++j) {
            f16x2 hh = fl[SL(bb * 256 + o + 16 * j)];
            xr[j] = (float)hh.x; xi[j] = (float)hh.y;
        }
        fftB_fwd(xr, xi, two.x, two.y);
#pragma unroll
        for (int j = 0; j < 16; ++j)
            fl[SL(bb * 256 + o + 16 * j)] = pk2(xr[j], xi[j]);
    }
    __syncthreads();
    {
        const f16x2* khp = Khat + ((size_t)h * 64 + k) * NFFT + 16 * tid;
        f16x2 kk[16];
#pragma unroll
        for (int j = 0; j < 16; ++j) kk[j] = khp[j];
#pragma unroll
        for (int j = 0; j < 16; ++j) {
            f16x2 hh = fl[SL(16 * tid + j)];
            xr[j] = (float)hh.x; xi[j] = (float)hh.y;
        }
        fftC_fwd(xr, xi);
#pragma unroll
        for (int j = 0; j < 16; ++j) {
            float kr = (float)kk[j].x, ki = (float)kk[j].y;
            float ar = xr[j], ai = xi[j];
            xr[j] = ar * kr - ai * ki;
            xi[j] = ar * ki + ai * kr;
        }
        fftC_inv(xr, xi);
#pragma unroll
        for (int j = 0; j < 16; ++j) fl[SL(16 * tid + j)] = pk2(xr[j], xi[j]);
    }
    __syncthreads();
    {
        int bb = tid >> 4, o = tid & 15;
#pragma unroll
        for (int j = 0; j < 16; ++j) {
            f16x2 hh = fl[SL(bb * 256 + o + 16 * j)];
            xr[j] = (float)hh.x; xi[j] = (float)hh.y;
        }
        fftB_inv(xr, xi, two.x, two.y);
#pragma unroll
        for (int j = 0; j < 16; ++j)
            fl[SL(bb * 256 + o + 16 * j)] = pk2(xr[j], xi[j]);
    }
    __syncthreads();
#pragma unroll
    for (int j = 0; j < 16; ++j) {
        f16x2 hh = fl[SL(p + 256 * j)];
        xr[j] = (float)hh.x; xi[j] = (float)hh.y;
    }
    fftA_inv(xr, xi, twp.x, twp.y);
#pragma unroll
    for (int j = 0; j < 8; ++j)  // only n<2048 needed
        col[p + 256 * j] = pk2(xr[j], xi[j]);
}

// ------ C: inverse v-FFT64 (Hermitian) + GELU -> actb[b][l][e] bf16 ----------
__global__ __launch_bounds__(256) void k_vifft(const f16x2* __restrict__ Xv,
                                               bf16* __restrict__ actb,
                                               const float2* __restrict__ tw) {
    __shared__ float Xre[64 * 66];
    __shared__ float Xim[64 * 66];
    int l0 = blockIdx.x * 64, h = blockIdx.y, b = blockIdx.z;
    int tid = threadIdx.x;
    for (int i = tid; i < 33 * 64; i += 256) {
        int k = i >> 6, lc = i & 63;
        f16x2 z = Xv[((size_t)(b * H_ + h) * 33 + k) * L_ + l0 + lc];
        Xre[k * 66 + lc] = (float)z.x; Xim[k * 66 + lc] = (float)z.y;
    }
    __syncthreads();
    for (int i = tid; i < 31 * 64; i += 256) {
        int k = 33 + (i >> 6), lc = i & 63;
        Xre[k * 66 + lc] =  Xre[(64 - k) * 66 + lc];
        Xim[k * 66 + lc] = -Xim[(64 - k) * 66 + lc];
    }
    fft64_rows<1>(Xre, Xim, tid, tw);
    bf16* dst = actb + ((size_t)(b * L_ + l0)) * E_ + h * 64;
#pragma unroll
    for (int it = 0; it < 2; ++it) {
        int c = tid + it * 256;
        int lc = c >> 3, m8 = (c & 7) * 8;
        unsigned short o[8];
#pragma unroll
        for (int j = 0; j < 8; ++j) {
            float x = Xre[drev64(m8 + j) * 66 + lc];
            float g = 0.5f * x * (1.0f + erff(x * 0.70710678118654752f));
            bf16 bb = __float2bfloat16(g);
            o[j] = *(unsigned short*)&bb;
        }
        *(ushort4*)(dst + (size_t)lc * E_ + m8)     = make_ushort4(o[0], o[1], o[2], o[3]);
        *(ushort4*)(dst + (size_t)lc * E_ + m8 + 4) = make_ushort4(o[4], o[5], o[6], o[7]);
    }
}

// -- fused: row = accbb(bf16) + sparse gather + emb; LayerNorm -> outp (fp32) --
__global__ __launch_bounds__(256) void k_spmm_ln(const int* __restrict__ nnz,
                                                 const int* __restrict__ idxs,
                                                 const float* __restrict__ vals,
                                                 const bf16* __restrict__ P,
                                                 const bf16* __restrict__ accbb,
                                                 const float* __restrict__ emb,
                                                 const float* __restrict__ gamma,
                                                 const float* __restrict__ beta,
                                                 float* __restrict__ outp) {
    __shared__ int sidx[CAP];
    __shared__ float sval[CAP];
    __shared__ float red[256];
    int l = blockIdx.x, b = blockIdx.y, tid = threadIdx.x;
    int n = nnz[l];
    for (int j = tid; j < n; j += 256) {
        sidx[j] = idxs[l * CAP + j];
        sval[j] = vals[l * CAP + j];
    }
    __syncthreads();
    size_t off = (size_t)tid * 4;
    size_t rowbase = ((size_t)(b * L_ + l)) * E_;
    ushort4 a4 = *(const ushort4*)(accbb + rowbase + off);
    float4 e4 = *(const float4*)(emb + rowbase + off);
    float x0 = bfu2f(a4.x) + e4.x;
    float x1 = bfu2f(a4.y) + e4.y;
    float x2 = bfu2f(a4.z) + e4.z;
    float x3 = bfu2f(a4.w) + e4.w;
    const bf16* Pb = P + (size_t)b * L_ * E_;
    for (int j = 0; j < n; ++j) {
        float v = sval[j];
        ushort4 p = *(const ushort4*)(Pb + (size_t)sidx[j] * E_ + off);
        x0 += v * bfu2f(p.x); x1 += v * bfu2f(p.y);
        x2 += v * bfu2f(p.z); x3 += v * bfu2f(p.w);
    }
    red[tid] = x0 + x1 + x2 + x3; __syncthreads();
    for (int o2 = 128; o2 > 0; o2 >>= 1) {
        if (tid < o2) red[tid] += red[tid + o2];
        __syncthreads();
    }
    float mu = red[0] * (1.0f / E_);
    __syncthreads();
    float d0 = x0 - mu, d1 = x1 - mu, d2 = x2 - mu, d3 = x3 - mu;
    red[tid] = d0 * d0 + d1 * d1 + d2 * d2 + d3 * d3; __syncthreads();
    for (int o2 = 128; o2 > 0; o2 >>= 1) {
        if (tid < o2) red[tid] += red[tid + o2];
        __syncthreads();
    }
    float inv = rsqrtf(red[0] * (1.0f / E_) + 1e-12f);
    float4 g4 = *(const float4*)(gamma + off);
    float4 b4 = *(const float4*)(beta + off);
    float4 o4;
    o4.x = d0 * inv * g4.x + b4.x;
    o4.y = d1 * inv * g4.y + b4.y;
    o4.z = d2 * inv * g4.z + b4.z;
    o4.w = d3 * inv * g4.w + b4.w;
    *(float4*)(outp + rowbase + off) = o4;
}

extern "C" void kernel_launch(void* const* d_in, const int* in_sizes, int n_in,
                              void* d_out, int out_size, void* d_ws, size_t ws_size,
                              hipStream_t stream) {
    const float* emb    = (const float*)d_in[0];
    const float* W1     = (const float*)d_in[1];
    const float* b1     = (const float*)d_in[2];
    const float* W2     = (const float*)d_in[3];
    const float* b2     = (const float*)d_in[4];
    const float* psfs   = (const float*)d_in[5];
    const float* W3     = (const float*)d_in[6];
    const float* b3     = (const float*)d_in[7];
    const float* sparse = (const float*)d_in[8];
    const float* gamma  = (const float*)d_in[9];
    const float* beta   = (const float*)d_in[10];
    float* outp = (float*)d_out;

    const size_t BLE  = (size_t)B_ * L_ * E_;
    const size_t EE   = (size_t)E_ * E_;
    const size_t KSZ  = (size_t)H_ * D_ * NFFT;        // f16x2 elems
    const size_t XVSZ = (size_t)B_ * H_ * 33 * L_;     // f16x2 elems

    bf16*   accbb      = (bf16*)d_ws;                  // 16.8 MB
    bf16*   pre_sparse = accbb + BLE;                  // 16.8 MB
    f16x2*  Khat       = (f16x2*)(pre_sparse + BLE);   // 16.8 MB
    f16x2*  Xv         = Khat + KSZ;                   // 17.3 MB
    bf16*   preb       = (bf16*)(Xv + XVSZ);           // 16.8 MB
    bf16*   actb       = preb + BLE;                   // 16.8 MB
    bf16*   W1b        = actb + BLE;                   // 3x 2.1 MB
    bf16*   W2b        = W1b + EE;
    bf16*   W3b        = W2b + EE;
    float2* twd        = (float2*)(W3b + EE);          // 32 KB
    int*    s_nnz      = (int*)(twd + NFFT);           // dedicated region (~2MB)
    int*    s_idx      = s_nnz + L_;
    float*  s_val      = (float*)(s_idx + (size_t)L_ * CAP);
    // psfT overlays Xv (dead before vfft writes Xv)
    float*  psfT       = (float*)Xv;

    // prologue: twiddle | emb->bf16 | W1..3->bf16 | psf transpose | sparse lists
    k_prologue<<<NB_TW + NB_CVT + NB_CVTW + NB_TF + NB_SP, 256, 0, stream>>>(
        emb, W1, W2, W3, psfs, sparse, twd, actb, W1b, psfT, s_nnz, s_idx, s_val);

    // merged: preb = bf16(emb @ W1^T + b1)  ||  build_khat
    k_gemm1_khat<<<2048, 256, 0, stream>>>(actb, W1b, b1, preb, psfT, Khat, twd);

    // merged: pre_sparse = GEMM2 || dfft(Khat) || vfft(preb)
    k_gemm2_dfft_vfft<<<4096, 256, 0, stream>>>(preb, W2b, b2, pre_sparse, Khat, Xv, twd);

    // fused per-(k,h,b) seq conv (in place)
    k_seqconv<<<dim3(33, H_, B_), 256, 0, stream>>>(Xv, Khat, twd);

    // inverse v-FFT + GELU -> actb
    k_vifft<<<dim3(L_ / 64, H_, B_), 256, 0, stream>>>(Xv, actb, twd);

    // accbb = bf16(conv @ W3^T + b3)
    k_gemm3<<<1024, 256, 0, stream>>>(actb, W3b, b3, accbb);

    // fused: out = LayerNorm(accbb + tril(sparse)@pre_sparse + emb)
    k_spmm_ln<<<dim3(L_, B_), 256, 0, stream>>>(
        s_nnz, s_idx, s_val, pre_sparse, accbb, emb, gamma, beta, outp);
}

// Round 22
// 195.433 us; speedup vs baseline: 1.1896x; 1.0070x over previous
//
#include <hip/hip_runtime.h>
#include <hip/hip_bf16.h>
#include <hip/hip_fp16.h>
#include <math.h>

#define B_ 4
#define L_ 2048
#define E_ 1024
#define H_ 16
#define D_ 64
#define NFFT 4096
#define CAP 128

typedef __hip_bfloat16 bf16;
typedef __attribute__((ext_vector_type(8))) short bf16x8;
typedef __attribute__((ext_vector_type(4))) float f32x4;
typedef __attribute__((ext_vector_type(2))) __fp16 f16x2;

typedef __attribute__((address_space(1))) const unsigned int gas_u32;
typedef __attribute__((address_space(3))) unsigned int las_u32;

__device__ __forceinline__ void gload_lds16(const void* g, void* l) {
    __builtin_amdgcn_global_load_lds((gas_u32*)g, (las_u32*)l, 16, 0, 0);
}

// padded LDS slot: +1 per 16 (<=2-way conflicts for all 3 phase patterns)
#define SL(i) ((i) + ((i) >> 4))
#define LDSN (NFFT + NFFT / 16)   // 4352
#define FST 65                    // f16x2 row stride for 64-row tiles

__device__ __forceinline__ float bfu2f(unsigned short u) {
    return __uint_as_float(((unsigned)u) << 16);
}
__device__ __forceinline__ f16x2 pk2(float a, float b) {
    return __builtin_amdgcn_cvt_pkrtz(a, b);
}

// base-4 3-digit reversal (involution)
__device__ __forceinline__ int drev64(int k) {
    return ((k & 3) << 4) | (k & 12) | ((k >> 4) & 3);
}

// stage-1 constants: C[j] = tw[256*j] = exp(-i*pi*j/8)
#define C1R 0.923879532511287f
#define C1I -0.382683432365090f
#define C2R 0.707106781186548f
#define C2I -0.707106781186548f
#define C3R 0.382683432365090f
#define C3I -0.923879532511287f

// ------- register radix-4 butterflies; w2=w1^2, w3=w1^3 derived in-reg -------
__device__ __forceinline__ void r4dif_w(float& x0r, float& x0i, float& x1r, float& x1i,
                                        float& x2r, float& x2i, float& x3r, float& x3i,
                                        float w1r, float w1i) {
    float a0r = x0r + x2r, a0i = x0i + x2i, a1r = x0r - x2r, a1i = x0i - x2i;
    float a2r = x1r + x3r, a2i = x1i + x3i, a3r = x1r - x3r, a3i = x1i - x3i;
    float y0r = a0r + a2r, y0i = a0i + a2i, y2r = a0r - a2r, y2i = a0i - a2i;
    float y1r = a1r + a3i, y1i = a1i - a3r, y3r = a1r - a3i, y3i = a1i + a3r;
    float w2r = w1r * w1r - w1i * w1i, w2i = 2.0f * w1r * w1i;
    float w3r = w2r * w1r - w2i * w1i, w3i = w2r * w1i + w2i * w1r;
    x0r = y0r; x0i = y0i;
    x1r = y1r * w1r - y1i * w1i; x1i = y1r * w1i + y1i * w1r;
    x2r = y2r * w2r - y2i * w2i; x2i = y2r * w2i + y2i * w2r;
    x3r = y3r * w3r - y3i * w3i; x3i = y3r * w3i + y3i * w3r;
}
__device__ __forceinline__ void r4dif_nt(float& x0r, float& x0i, float& x1r, float& x1i,
                                         float& x2r, float& x2i, float& x3r, float& x3i) {
    float a0r = x0r + x2r, a0i = x0i + x2i, a1r = x0r - x2r, a1i = x0i - x2i;
    float a2r = x1r + x3r, a2i = x1i + x3i, a3r = x1r - x3r, a3i = x1i - x3i;
    x0r = a0r + a2r; x0i = a0i + a2i;
    x2r = a0r - a2r; x2i = a0i - a2i;
    float y1r = a1r + a3i, y1i = a1i - a3r, y3r = a1r - a3i, y3i = a1i + a3r;
    x1r = y1r; x1i = y1i; x3r = y3r; x3i = y3i;
}
__device__ __forceinline__ void r4dit_w(float& x0r, float& x0i, float& x1r, float& x1i,
                                        float& x2r, float& x2i, float& x3r, float& x3i,
                                        float w1r, float w1i) {
    float w2r = w1r * w1r - w1i * w1i, w2i = 2.0f * w1r * w1i;
    float w3r = w2r * w1r - w2i * w1i, w3i = w2r * w1i + w2i * w1r;
    float z1r = x1r * w1r + x1i * w1i, z1i = x1i * w1r - x1r * w1i;
    float z2r = x2r * w2r + x2i * w2i, z2i = x2i * w2r - x2r * w2i;
    float z3r = x3r * w3r + x3i * w3i, z3i = x3i * w3r - x3r * w3i;
    float b0r = x0r + z2r, b0i = x0i + z2i, b1r = x0r - z2r, b1i = x0i - z2i;
    float b2r = z1r + z3r, b2i = z1i + z3i, b3r = z1r - z3r, b3i = z1i - z3i;
    x0r = b0r + b2r; x0i = b0i + b2i;
    x2r = b0r - b2r; x2i = b0i - b2i;
    x1r = b1r - b3i; x1i = b1i + b3r;
    x3r = b1r + b3i; x3i = b1i - b3r;
}
__device__ __forceinline__ void r4dit_nt(float& x0r, float& x0i, float& x1r, float& x1i,
                                         float& x2r, float& x2i, float& x3r, float& x3i) {
    float b0r = x0r + x2r, b0i = x0i + x2i, b1r = x0r - x2r, b1i = x0i - x2i;
    float b2r = x1r + x3r, b2i = x1i + x3i, b3r = x1r - x3r, b3i = x1i - x3i;
    x0r = b0r + b2r; x0i = b0i + b2i;
    x2r = b0r - b2r; x2i = b0i - b2i;
    x1r = b1r - b3i; x1i = b1i + b3r;
    x3r = b1r + b3i; x3i = b1i - b3r;
}

// ---- phase A (stages 0,1): thread p owns X[j]=a[p+256j]; wp = tw[p] ---------
__device__ __forceinline__ void fftA_fwd(float* xr, float* xi, float wpr, float wpi) {
    r4dif_w(xr[0], xi[0], xr[4], xi[4], xr[8], xi[8], xr[12], xi[12], wpr, wpi);
    r4dif_w(xr[1], xi[1], xr[5], xi[5], xr[9], xi[9], xr[13], xi[13],
            wpr * C1R - wpi * C1I, wpr * C1I + wpi * C1R);
    r4dif_w(xr[2], xi[2], xr[6], xi[6], xr[10], xi[10], xr[14], xi[14],
            wpr * C2R - wpi * C2I, wpr * C2I + wpi * C2R);
    r4dif_w(xr[3], xi[3], xr[7], xi[7], xr[11], xi[11], xr[15], xi[15],
            wpr * C3R - wpi * C3I, wpr * C3I + wpi * C3R);
    float s2r = wpr * wpr - wpi * wpi, s2i = 2.0f * wpr * wpi;
    float w4r = s2r * s2r - s2i * s2i, w4i = 2.0f * s2r * s2i;
#pragma unroll
    for (int g = 0; g < 4; ++g)
        r4dif_w(xr[4 * g], xi[4 * g], xr[4 * g + 1], xi[4 * g + 1], xr[4 * g + 2],
                xi[4 * g + 2], xr[4 * g + 3], xi[4 * g + 3], w4r, w4i);
}
__device__ __forceinline__ void fftA_inv(float* xr, float* xi, float wpr, float wpi) {
    float s2r = wpr * wpr - wpi * wpi, s2i = 2.0f * wpr * wpi;
    float w4r = s2r * s2r - s2i * s2i, w4i = 2.0f * s2r * s2i;
#pragma unroll
    for (int g = 0; g < 4; ++g)
        r4dit_w(xr[4 * g], xi[4 * g], xr[4 * g + 1], xi[4 * g + 1], xr[4 * g + 2],
                xi[4 * g + 2], xr[4 * g + 3], xi[4 * g + 3], w4r, w4i);
    r4dit_w(xr[0], xi[0], xr[4], xi[4], xr[8], xi[8], xr[12], xi[12], wpr, wpi);
    r4dit_w(xr[1], xi[1], xr[5], xi[5], xr[9], xi[9], xr[13], xi[13],
            wpr * C1R - wpi * C1I, wpr * C1I + wpi * C1R);
    r4dit_w(xr[2], xi[2], xr[6], xi[6], xr[10], xi[10], xr[14], xi[14],
            wpr * C2R - wpi * C2I, wpr * C2I + wpi * C2R);
    r4dit_w(xr[3], xi[3], xr[7], xi[7], xr[11], xi[11], xr[15], xi[15],
            wpr * C3R - wpi * C3I, wpr * C3I + wpi * C3R);
}
// ---- phase B (stages 2,3): thread (b,o) owns X[j]=a[b*256+o+16j]; wo=tw[16o]
__device__ __forceinline__ void fftB_fwd(float* xr, float* xi, float wor, float woi) {
    r4dif_w(xr[0], xi[0], xr[4], xi[4], xr[8], xi[8], xr[12], xi[12], wor, woi);
    r4dif_w(xr[1], xi[1], xr[5], xi[5], xr[9], xi[9], xr[13], xi[13],
            wor * C1R - woi * C1I, wor * C1I + woi * C1R);
    r4dif_w(xr[2], xi[2], xr[6], xi[6], xr[10], xi[10], xr[14], xi[14],
            wor * C2R - woi * C2I, wor * C2I + woi * C2R);
    r4dif_w(xr[3], xi[3], xr[7], xi[7], xr[11], xi[11], xr[15], xi[15],
            wor * C3R - woi * C3I, wor * C3I + woi * C3R);
    float s2r = wor * wor - woi * woi, s2i = 2.0f * wor * woi;
    float w4r = s2r * s2r - s2i * s2i, w4i = 2.0f * s2r * s2i;
#pragma unroll
    for (int g = 0; g < 4; ++g)
        r4dif_w(xr[4 * g], xi[4 * g], xr[4 * g + 1], xi[4 * g + 1], xr[4 * g + 2],
                xi[4 * g + 2], xr[4 * g + 3], xi[4 * g + 3], w4r, w4i);
}
__device__ __forceinline__ void fftB_inv(float* xr, float* xi, float wor, float woi) {
    float s2r = wor * wor - woi * woi, s2i = 2.0f * wor * woi;
    float w4r = s2r * s2r - s2i * s2i, w4i = 2.0f * s2r * s2i;
#pragma unroll
    for (int g = 0; g < 4; ++g)
        r4dit_w(xr[4 * g], xi[4 * g], xr[4 * g + 1], xi[4 * g + 1], xr[4 * g + 2],
                xi[4 * g + 2], xr[4 * g + 3], xi[4 * g + 3], w4r, w4i);
    r4dit_w(xr[0], xi[0], xr[4], xi[4], xr[8], xi[8], xr[12], xi[12], wor, woi);
    r4dit_w(xr[1], xi[1], xr[5], xi[5], xr[9], xi[9], xr[13], xi[13],
            wor * C1R - woi * C1I, wor * C1I + woi * C1R);
    r4dit_w(xr[2], xi[2], xr[6], xi[6], xr[10], xi[10], xr[14], xi[14],
            wor * C2R - woi * C2I, wor * C2I + woi * C2R);
    r4dit_w(xr[3], xi[3], xr[7], xi[7], xr[11], xi[11], xr[15], xi[15],
            wor * C3R - woi * C3I, wor * C3I + woi * C3R);
}
// ---- phase C (stages 4,5): thread t owns X[j]=a[16t+j]; constant twiddles ---
__device__ __forceinline__ void fftC_fwd(float* xr, float* xi) {
    r4dif_w(xr[0], xi[0], xr[4], xi[4], xr[8], xi[8], xr[12], xi[12], 1.0f, 0.0f);
    r4dif_w(xr[1], xi[1], xr[5], xi[5], xr[9], xi[9], xr[13], xi[13], C1R, C1I);
    r4dif_w(xr[2], xi[2], xr[6], xi[6], xr[10], xi[10], xr[14], xi[14], C2R, C2I);
    r4dif_w(xr[3], xi[3], xr[7], xi[7], xr[11], xi[11], xr[15], xi[15], C3R, C3I);
#pragma unroll
    for (int g = 0; g < 4; ++g)
        r4dif_nt(xr[4 * g], xi[4 * g], xr[4 * g + 1], xi[4 * g + 1], xr[4 * g + 2],
                 xi[4 * g + 2], xr[4 * g + 3], xi[4 * g + 3]);
}
__device__ __forceinline__ void fftC_inv(float* xr, float* xi) {
#pragma unroll
    for (int g = 0; g < 4; ++g)
        r4dit_nt(xr[4 * g], xi[4 * g], xr[4 * g + 1], xi[4 * g + 1], xr[4 * g + 2],
                 xi[4 * g + 2], xr[4 * g + 3], xi[4 * g + 3]);
    r4dit_w(xr[0], xi[0], xr[4], xi[4], xr[8], xi[8], xr[12], xi[12], 1.0f, 0.0f);
    r4dit_w(xr[1], xi[1], xr[5], xi[5], xr[9], xi[9], xr[13], xi[13], C1R, C1I);
    r4dit_w(xr[2], xi[2], xr[6], xi[6], xr[10], xi[10], xr[14], xi[14], C2R, C2I);
    r4dit_w(xr[3], xi[3], xr[7], xi[7], xr[11], xi[11], xr[15], xi[15], C3R, C3I);
}

// ---- batched 64-pt radix-4 over rows, f16x2 LDS, layout idx = row*STRIDE+col
// natural-in -> digit-rev-out. CONJ=0 fwd, CONJ=1 unnormalized inverse.
template <int CONJ, int STRIDE>
__device__ inline void fft64h(f16x2* __restrict__ X, int tid,
                              const float2* __restrict__ tw) {
    for (int st = 0; st < 3; ++st) {
        int q = 1 << (4 - 2 * st);
        __syncthreads();
        for (int it = 0; it < 4; ++it) {
            int w = tid + (it << 8);
            int lc = w & 63, bc = w >> 6;
            int p = bc & (q - 1);
            int basev = ((bc & ~(q - 1)) << 2) | p;
            int i0 = basev * STRIDE + lc, i1 = i0 + q * STRIDE,
                i2 = i1 + q * STRIDE, i3 = i2 + q * STRIDE;
            f16x2 h0 = X[i0], h1 = X[i1], h2 = X[i2], h3 = X[i3];
            float x0r = (float)h0.x, x0i = (float)h0.y;
            float x1r = (float)h1.x, x1i = (float)h1.y;
            float x2r = (float)h2.x, x2i = (float)h2.y;
            float x3r = (float)h3.x, x3i = (float)h3.y;
            float a0r = x0r + x2r, a0i = x0i + x2i;
            float a1r = x0r - x2r, a1i = x0i - x2i;
            float a2r = x1r + x3r, a2i = x1i + x3i;
            float a3r = x1r - x3r, a3i = x1i - x3i;
            float y0r = a0r + a2r, y0i = a0i + a2i;
            float y2r = a0r - a2r, y2i = a0i - a2i;
            float y1r, y1i, y3r, y3i;
            if (!CONJ) {
                y1r = a1r + a3i; y1i = a1i - a3r;
                y3r = a1r - a3i; y3i = a1i + a3r;
            } else {
                y1r = a1r - a3i; y1i = a1i + a3r;
                y3r = a1r + a3i; y3i = a1i - a3r;
            }
            int e = (p << (2 * st)) * 64;
            float2 w1 = tw[e];
            float w1x = w1.x, w1y = CONJ ? -w1.y : w1.y;
            float w2x = w1x * w1x - w1y * w1y, w2y = 2.0f * w1x * w1y;
            float w3x = w2x * w1x - w2y * w1y, w3y = w2x * w1y + w2y * w1x;
            X[i0] = pk2(y0r, y0i);
            X[i1] = pk2(y1r * w1x - y1i * w1y, y1r * w1y + y1i * w1x);
            X[i2] = pk2(y2r * w2x - y2i * w2y, y2r * w2y + y2i * w2x);
            X[i3] = pk2(y3r * w3x - y3i * w3y, y3r * w3y + y3i * w3x);
        }
    }
    __syncthreads();
}

// ---- merged prologue: twiddle | emb cvt | W cvt | psf transpose | sparse ----
#define NB_TW 16
#define NB_CVT 8192
#define NB_CVTW 3072
#define NB_TF 512
#define NB_SP 2048
__global__ __launch_bounds__(256) void k_prologue(const float* __restrict__ emb,
                                                  const float* __restrict__ W1,
                                                  const float* __restrict__ W2,
                                                  const float* __restrict__ W3,
                                                  const float* __restrict__ psfs,
                                                  const float* __restrict__ Sp,
                                                  float2* __restrict__ tw,
                                                  bf16* __restrict__ embb,
                                                  bf16* __restrict__ Wb,
                                                  float* __restrict__ psfT,
                                                  int* __restrict__ nnz,
                                                  int* __restrict__ idxs,
                                                  float* __restrict__ vals) {
    __shared__ float tile[64][65];
    __shared__ int cnt;
    int tid = threadIdx.x;
    int blk = blockIdx.x;
    if (blk < NB_TW) {
        int k = blk * 256 + tid;
        float ang = -(float)k * (float)(M_PI / 2048.0);
        tw[k] = make_float2(cosf(ang), sinf(ang));
        return;
    }
    blk -= NB_TW;
    if (blk < NB_CVT) {
        int i = (blk * 256 + tid) * 4;
        float4 v = *(const float4*)(emb + i);
        bf16 tmp[4];
        tmp[0] = __float2bfloat16(v.x); tmp[1] = __float2bfloat16(v.y);
        tmp[2] = __float2bfloat16(v.z); tmp[3] = __float2bfloat16(v.w);
        *(ushort4*)(embb + i) = *(ushort4*)tmp;
        return;
    }
    blk -= NB_CVT;
    if (blk < NB_CVTW) {
        int w = blk >> 10;
        const float* src = (w == 0) ? W1 : (w == 1) ? W2 : W3;
        int i = ((blk & 1023) * 256 + tid) * 4;
        float4 v = *(const float4*)(src + i);
        bf16 tmp[4];
        tmp[0] = __float2bfloat16(v.x); tmp[1] = __float2bfloat16(v.y);
        tmp[2] = __float2bfloat16(v.z); tmp[3] = __float2bfloat16(v.w);
        *(ushort4*)(Wb + (size_t)w * E_ * E_ + i) = *(ushort4*)tmp;
        return;
    }
    blk -= NB_CVTW;
    if (blk < NB_TF) {
        int z = blk >> 5;
        int r0 = (blk & 31) * 64;
        const float* in = psfs + (size_t)z * (2 * L_ - 1) * D_;
        float* out = psfT + (size_t)z * D_ * L_;
        int tx4 = (tid & 15) * 4, ty = tid >> 4;
#pragma unroll
        for (int k = 0; k < 4; ++k) {
            int r = ty + 16 * k;
            float4 v = *(const float4*)&in[(size_t)(r0 + r) * D_ + tx4];
            tile[r][tx4 + 0] = v.x; tile[r][tx4 + 1] = v.y;
            tile[r][tx4 + 2] = v.z; tile[r][tx4 + 3] = v.w;
        }
        __syncthreads();
#pragma unroll
        for (int k = 0; k < 4; ++k) {
            int c = ty + 16 * k;
            float4 w;
            w.x = tile[tx4 + 0][c]; w.y = tile[tx4 + 1][c];
            w.z = tile[tx4 + 2][c]; w.w = tile[tx4 + 3][c];
            *(float4*)&out[(size_t)c * L_ + r0 + tx4] = w;
        }
        return;
    }
    blk -= NB_TF;
    {
        int l = blk;
        if (tid == 0) cnt = 0;
        __syncthreads();
        const float* row = Sp + (size_t)l * L_;
        for (int s = tid; s <= l; s += 256) {
            float v = row[s];
            if (v != 0.0f) {
                int slot = atomicAdd(&cnt, 1);
                if (slot < CAP) { idxs[l * CAP + slot] = s; vals[l * CAP + slot] = v; }
            }
        }
        __syncthreads();
        if (tid == 0) nnz[l] = min(cnt, CAP);
    }
}

// ---- GEMM body (64x128 tile, BK=64, swizzled LDS, XCD swizzle), bf16 out ----
__device__ __forceinline__ void gemm_body(void* smemraw, int flat, int nwgx,
                                          const bf16* __restrict__ A,
                                          const bf16* __restrict__ Wt,
                                          const float* __restrict__ bias,
                                          bf16* __restrict__ Cb,
                                          int nwg, int N, int K) {
    bf16* As = (bf16*)smemraw;        // 64*64
    bf16* Bs = As + 64 * 64;          // 128*64
    int tid = threadIdx.x;
    int lane = tid & 63, w = tid >> 6;
    int wr = w >> 1, wc = w & 1;

    int cpx = nwg >> 3;
    int swz = (flat & 7) * cpx + (flat >> 3);
    int bx = (swz % nwgx) * 128;
    int by = (swz / nwgx) * 64;

    f32x4 zz = {0.0f, 0.0f, 0.0f, 0.0f};
    f32x4 acc[2][4];
#pragma unroll
    for (int m = 0; m < 2; ++m)
#pragma unroll
        for (int n = 0; n < 4; ++n) acc[m][n] = zz;

    int koff = (lane >> 4) * 8;
    int rsub = lane & 15;

    for (int k0 = 0; k0 < K; k0 += 64) {
#pragma unroll
        for (int i = 0; i < 2; ++i) {
            int c = tid + i * 256;
            int row = c >> 3;
            int kb = (c & 7) * 8;
            int kbs = kb ^ ((row & 7) << 3);
            gload_lds16(A + (size_t)(by + row) * K + k0 + kbs, &As[c * 8]);
        }
#pragma unroll
        for (int i = 0; i < 4; ++i) {
            int c = tid + i * 256;
            int row = c >> 3;
            int kb = (c & 7) * 8;
            int kbs = kb ^ ((row & 7) << 3);
            gload_lds16(Wt + (size_t)(bx + row) * K + k0 + kbs, &Bs[c * 8]);
        }
        __syncthreads();
#pragma unroll
        for (int half = 0; half < 2; ++half) {
            int ko = koff + half * 32;
            bf16x8 af[2], bfv[4];
#pragma unroll
            for (int m = 0; m < 2; ++m) {
                int R = wr * 32 + m * 16 + rsub;
                af[m] = *(const bf16x8*)&As[R * 64 + (ko ^ ((R & 7) << 3))];
            }
#pragma unroll
            for (int n = 0; n < 4; ++n) {
                int R = wc * 64 + n * 16 + rsub;
                bfv[n] = *(const bf16x8*)&Bs[R * 64 + (ko ^ ((R & 7) << 3))];
            }
#pragma unroll
            for (int m = 0; m < 2; ++m)
#pragma unroll
                for (int n = 0; n < 4; ++n)
                    acc[m][n] = __builtin_amdgcn_mfma_f32_16x16x32_bf16(af[m], bfv[n], acc[m][n], 0, 0, 0);
        }
        __syncthreads();
    }

    int cq = (lane >> 4) * 4;
    int cr = lane & 15;
#pragma unroll
    for (int m = 0; m < 2; ++m) {
        int row0 = by + wr * 32 + m * 16 + cq;
#pragma unroll
        for (int n = 0; n < 4; ++n) {
            int col = bx + wc * 64 + n * 16 + cr;
            float bv = bias[col];
#pragma unroll
            for (int j = 0; j < 4; ++j) {
                float v = acc[m][n][j] + bv;
                Cb[(size_t)(row0 + j) * N + col] = __float2bfloat16(v);
            }
        }
    }
}

// ---- build_khat body: PSF softmax + FULL K4096 + fwd FFT --------------------
__device__ __forceinline__ void khat_body(void* smemraw, int blk,
                                          const float* __restrict__ psfT,
                                          f16x2* __restrict__ Khat,
                                          const float2* __restrict__ tw) {
    f16x2* fl = (f16x2*)smemraw;
    float* red = (float*)(fl + LDSN);
    int u = blk & 63, h = blk >> 6;
    int tid = threadIdx.x;
    const float* col = psfT + ((size_t)(h * D_ + u)) * L_;
    int p = tid;

    float2 twp = tw[p];
    float2 two = tw[(tid & 15) * 16];

    float v[8];
#pragma unroll
    for (int j = 0; j < 8; ++j) v[j] = col[p + 256 * j];

    float lm = v[0];
#pragma unroll
    for (int j = 1; j < 8; ++j) lm = fmaxf(lm, v[j]);
    red[tid] = lm; __syncthreads();
    for (int off = 128; off > 0; off >>= 1) {
        if (tid < off) red[tid] = fmaxf(red[tid], red[tid + off]);
        __syncthreads();
    }
    float M = fmaxf(red[0], 0.0f);
    __syncthreads();

    float e[8];
    float ls = 0.0f;
#pragma unroll
    for (int j = 0; j < 8; ++j) { e[j] = expf(v[j] - M); ls += e[j]; }
    red[tid] = ls; __syncthreads();
    for (int off = 128; off > 0; off >>= 1) {
        if (tid < off) red[tid] += red[tid + off];
        __syncthreads();
    }
    float Z = red[0] + (float)(L_ - 1) * expf(-M);
    float invZ = 1.0f / Z;
    float cval = expf(-M) * invZ;

    float xr[16], xi[16];
#pragma unroll
    for (int j = 0; j < 16; ++j) {
        int i = p + 256 * j;
        xr[j] = (j < 8) ? e[j] * invZ : ((i == 2048) ? 0.0f : cval);
        xi[j] = 0.0f;
    }
    __syncthreads();

    fftA_fwd(xr, xi, twp.x, twp.y);
#pragma unroll
    for (int j = 0; j < 16; ++j) fl[SL(p + 256 * j)] = pk2(xr[j], xi[j]);
    __syncthreads();
    {
        int bb = tid >> 4, o = tid & 15;
#pragma unroll
        for (int j = 0; j < 16; ++j) {
            f16x2 hh = fl[SL(bb * 256 + o + 16 * j)];
            xr[j] = (float)hh.x; xi[j] = (float)hh.y;
        }
        fftB_fwd(xr, xi, two.x, two.y);
#pragma unroll
        for (int j = 0; j < 16; ++j)
            fl[SL(bb * 256 + o + 16 * j)] = pk2(xr[j], xi[j]);
    }
    __syncthreads();
#pragma unroll
    for (int j = 0; j < 16; ++j) {
        f16x2 hh = fl[SL(16 * tid + j)];
        xr[j] = (float)hh.x; xi[j] = (float)hh.y;
    }
    fftC_fwd(xr, xi);

    float sc = 1.0f / (float)NFFT;
    f16x2* outp = Khat + ((size_t)h * D_ + u) * NFFT + 16 * tid;
#pragma unroll
    for (int j = 0; j < 16; ++j) outp[j] = pk2(xr[j] * sc, xi[j] * sc);
}

// ---- dfft body: in-place FFT64 over u of Khat (+1/64, natural-k order) ------
// f16x2 LDS, layout [u*64 + fc]
__device__ __forceinline__ void dfft_body(void* smemraw, int blk,
                                          f16x2* __restrict__ Khat,
                                          const float2* __restrict__ tw) {
    f16x2* X = (f16x2*)smemraw;
    int tid = threadIdx.x;
    int f0 = (blk & 63) * 64, h = blk >> 6;
    f16x2* kb = Khat + (size_t)h * D_ * NFFT;
    for (int i = tid; i < 4096; i += 256) {
        int uu = i >> 6, fc = i & 63;
        X[i] = kb[(size_t)uu * NFFT + f0 + fc];
    }
    fft64h<0, 64>(X, tid, tw);
    float sc = 1.0f / 64.0f;
    for (int i = tid; i < 4096; i += 256) {
        int s = i >> 6, fc = i & 63;
        f16x2 v = X[i];
        kb[(size_t)drev64(s) * NFFT + f0 + fc] = pk2((float)v.x * sc, (float)v.y * sc);
    }
}

// ---- vfft body: preb[b][l][e] -> Xv[b][h][k=0..32][l], f16x2 LDS ------------
__device__ __forceinline__ void vfft_body(void* smemraw, int blk,
                                          const bf16* __restrict__ preb,
                                          f16x2* __restrict__ Xv,
                                          const float2* __restrict__ tw) {
    f16x2* X = (f16x2*)smemraw;
    int tid = threadIdx.x;
    int l0 = (blk & 31) * 64, h = (blk >> 5) & 15, b = blk >> 9;
    const bf16* src = preb + ((size_t)(b * L_ + l0)) * E_ + h * 64;
#pragma unroll
    for (int it = 0; it < 2; ++it) {
        int c = tid + it * 256;
        int lc = c >> 3, v8 = (c & 7) * 8;
        bf16x8 xv8 = *(const bf16x8*)(src + (size_t)lc * E_ + v8);
#pragma unroll
        for (int j = 0; j < 8; ++j)
            X[(v8 + j) * FST + lc] = pk2(bfu2f((unsigned short)xv8[j]), 0.0f);
    }
    fft64h<0, FST>(X, tid, tw);
    for (int i = tid; i < 33 * 64; i += 256) {
        int k = i >> 6, lc = i & 63;
        Xv[((size_t)(b * H_ + h) * 33 + k) * L_ + l0 + lc] = X[drev64(k) * FST + lc];
    }
}

// ---- merged: [0,1024) GEMM1 | [1024,2048) build_khat ------------------------
__global__ __launch_bounds__(256) void k_gemm1_khat(const bf16* __restrict__ A,
                                                    const bf16* __restrict__ Wt,
                                                    const float* __restrict__ bias,
                                                    bf16* __restrict__ Cb,
                                                    const float* __restrict__ psfT,
                                                    f16x2* __restrict__ Khat,
                                                    const float2* __restrict__ tw) {
    __shared__ __align__(16) char smem[24576];
    int blk = blockIdx.x;
    if (blk < 1024)
        gemm_body(smem, blk, 8, A, Wt, bias, Cb, 1024, E_, E_);
    else
        khat_body(smem, blk - 1024, psfT, Khat, tw);
}

// ---- merged: [0,1024) GEMM2 | [1024,2048) dfft | [2048,4096) vfft -----------
// f16x2 FFT LDS shrinks the arena to the GEMM's 24.5KB -> 6 blocks/CU all branches
__global__ __launch_bounds__(256) void k_gemm2_dfft_vfft(const bf16* __restrict__ A,
                                                         const bf16* __restrict__ Wt,
                                                         const float* __restrict__ bias,
                                                         bf16* __restrict__ Cb,
                                                         f16x2* __restrict__ Khat,
                                                         f16x2* __restrict__ Xv,
                                                         const float2* __restrict__ tw) {
    __shared__ __align__(16) char smem[24576];
    int blk = blockIdx.x;
    if (blk < 1024)
        gemm_body(smem, blk, 8, A, Wt, bias, Cb, 1024, E_, E_);
    else if (blk < 2048)
        dfft_body(smem, blk - 1024, Khat, tw);
    else
        vfft_body(smem, blk - 2048, A, Xv, tw);
}

// ---- standalone GEMM3 -------------------------------------------------------
__global__ __launch_bounds__(256) void k_gemm3(const bf16* __restrict__ A,
                                               const bf16* __restrict__ Wt,
                                               const float* __restrict__ bias,
                                               bf16* __restrict__ Cb) {
    __shared__ __align__(16) char smem[24576];
    gemm_body(smem, blockIdx.x, 8, A, Wt, bias, Cb, 1024, E_, E_);
}

// ------ B: fused seq conv per (k,h,b): FFT4096 -> cmul Khat -> IFFT4096 ------
__global__ __launch_bounds__(256) void k_seqconv(f16x2* __restrict__ Xv,
                                                 const f16x2* __restrict__ Khat,
                                                 const float2* __restrict__ tw) {
    __shared__ f16x2 fl[LDSN];
    int k = blockIdx.x, h = blockIdx.y, b = blockIdx.z;
    int tid = threadIdx.x, p = tid;
    f16x2* col = Xv + ((size_t)(b * H_ + h) * 33 + k) * L_;

    float2 twp = tw[p];
    float2 two = tw[(tid & 15) * 16];

    float xr[16], xi[16];
#pragma unroll
    for (int j = 0; j < 16; ++j) {
        if (j < 8) {
            f16x2 z = col[p + 256 * j];
            xr[j] = (float)z.x; xi[j] = (float)z.y;
        } else { xr[j] = 0.0f; xi[j] = 0.0f; }
    }
    fftA_fwd(xr, xi, twp.x, twp.y);
#pragma unroll
    for (int j = 0; j < 16; ++j) fl[SL(p + 256 * j)] = pk2(xr[j], xi[j]);
    __syncthreads();
    {
        int bb = tid >> 4, o = tid & 15;
#pragma unroll
        for (int j = 0; j < 16; ++j) {
            f16x2 hh = fl[SL(bb * 256 + o + 16 * j)];
            xr[j] = (float)hh.x; xi[j] = (float)hh.y;
        }
        fftB_fwd(xr, xi, two.x, two.y);
#pragma unroll
        for (int j = 0; j < 16; ++j)
            fl[SL(bb * 256 + o + 16 * j)] = pk2(xr[j], xi[j]);
    }
    __syncthreads();
    {
        const f16x2* khp = Khat + ((size_t)h * 64 + k) * NFFT + 16 * tid;
        f16x2 kk[16];
#pragma unroll
        for (int j = 0; j < 16; ++j) kk[j] = khp[j];
#pragma unroll
        for (int j = 0; j < 16; ++j) {
            f16x2 hh = fl[SL(16 * tid + j)];
            xr[j] = (float)hh.x; xi[j] = (float)hh.y;
        }
        fftC_fwd(xr, xi);
#pragma unroll
        for (int j = 0; j < 16; ++j) {
            float kr = (float)kk[j].x, ki = (float)kk[j].y;
            float ar = xr[j], ai = xi[j];
            xr[j] = ar * kr - ai * ki;
            xi[j] = ar * ki + ai * kr;
        }
        fftC_inv(xr, xi);
#pragma unroll
        for (int j = 0; j < 16; ++j) fl[SL(16 * tid + j)] = pk2(xr[j], xi[j]);
    }
    __syncthreads();
    {
        int bb = tid >> 4, o = tid & 15;
#pragma unroll
        for (int j = 0; j < 16; ++j) {
            f16x2 hh = fl[SL(bb * 256 + o + 16 * j)];
            xr[j] = (float)hh.x; xi[j] = (float)hh.y;
        }
        fftB_inv(xr, xi, two.x, two.y);
#pragma unroll
        for (int j = 0; j < 16; ++j)
            fl[SL(bb * 256 + o + 16 * j)] = pk2(xr[j], xi[j]);
    }
    __syncthreads();
#pragma unroll
    for (int j = 0; j < 16; ++j) {
        f16x2 hh = fl[SL(p + 256 * j)];
        xr[j] = (float)hh.x; xi[j] = (float)hh.y;
    }
    fftA_inv(xr, xi, twp.x, twp.y);
#pragma unroll
    for (int j = 0; j < 8; ++j)  // only n<2048 needed
        col[p + 256 * j] = pk2(xr[j], xi[j]);
}

// ------ C: inverse v-FFT64 (Hermitian) + GELU -> actb[b][l][e] bf16 ----------
// f16x2 LDS (16.6KB)
__global__ __launch_bounds__(256) void k_vifft(const f16x2* __restrict__ Xv,
                                               bf16* __restrict__ actb,
                                               const float2* __restrict__ tw) {
    __shared__ f16x2 X[64 * FST];
    int l0 = blockIdx.x * 64, h = blockIdx.y, b = blockIdx.z;
    int tid = threadIdx.x;
    for (int i = tid; i < 33 * 64; i += 256) {
        int k = i >> 6, lc = i & 63;
        X[k * FST + lc] = Xv[((size_t)(b * H_ + h) * 33 + k) * L_ + l0 + lc];
    }
    __syncthreads();
    for (int i = tid; i < 31 * 64; i += 256) {
        int k = 33 + (i >> 6), lc = i & 63;
        f16x2 z = X[(64 - k) * FST + lc];
        X[k * FST + lc] = pk2((float)z.x, -(float)z.y);
    }
    fft64h<1, FST>(X, tid, tw);
    bf16* dst = actb + ((size_t)(b * L_ + l0)) * E_ + h * 64;
#pragma unroll
    for (int it = 0; it < 2; ++it) {
        int c = tid + it * 256;
        int lc = c >> 3, m8 = (c & 7) * 8;
        unsigned short o[8];
#pragma unroll
        for (int j = 0; j < 8; ++j) {
            float x = (float)X[drev64(m8 + j) * FST + lc].x;
            float g = 0.5f * x * (1.0f + erff(x * 0.70710678118654752f));
            bf16 bb = __float2bfloat16(g);
            o[j] = *(unsigned short*)&bb;
        }
        *(ushort4*)(dst + (size_t)lc * E_ + m8)     = make_ushort4(o[0], o[1], o[2], o[3]);
        *(ushort4*)(dst + (size_t)lc * E_ + m8 + 4) = make_ushort4(o[4], o[5], o[6], o[7]);
    }
}

// -- fused: row = accbb(bf16) + sparse gather + emb; LayerNorm -> outp (fp32) --
__global__ __launch_bounds__(256) void k_spmm_ln(const int* __restrict__ nnz,
                                                 const int* __restrict__ idxs,
                                                 const float* __restrict__ vals,
                                                 const bf16* __restrict__ P,
                                                 const bf16* __restrict__ accbb,
                                                 const float* __restrict__ emb,
                                                 const float* __restrict__ gamma,
                                                 const float* __restrict__ beta,
                                                 float* __restrict__ outp) {
    __shared__ int sidx[CAP];
    __shared__ float sval[CAP];
    __shared__ float red[256];
    int l = blockIdx.x, b = blockIdx.y, tid = threadIdx.x;
    int n = nnz[l];
    for (int j = tid; j < n; j += 256) {
        sidx[j] = idxs[l * CAP + j];
        sval[j] = vals[l * CAP + j];
    }
    __syncthreads();
    size_t off = (size_t)tid * 4;
    size_t rowbase = ((size_t)(b * L_ + l)) * E_;
    ushort4 a4 = *(const ushort4*)(accbb + rowbase + off);
    float4 e4 = *(const float4*)(emb + rowbase + off);
    float x0 = bfu2f(a4.x) + e4.x;
    float x1 = bfu2f(a4.y) + e4.y;
    float x2 = bfu2f(a4.z) + e4.z;
    float x3 = bfu2f(a4.w) + e4.w;
    const bf16* Pb = P + (size_t)b * L_ * E_;
    for (int j = 0; j < n; ++j) {
        float v = sval[j];
        ushort4 p = *(const ushort4*)(Pb + (size_t)sidx[j] * E_ + off);
        x0 += v * bfu2f(p.x); x1 += v * bfu2f(p.y);
        x2 += v * bfu2f(p.z); x3 += v * bfu2f(p.w);
    }
    red[tid] = x0 + x1 + x2 + x3; __syncthreads();
    for (int o2 = 128; o2 > 0; o2 >>= 1) {
        if (tid < o2) red[tid] += red[tid + o2];
        __syncthreads();
    }
    float mu = red[0] * (1.0f / E_);
    __syncthreads();
    float d0 = x0 - mu, d1 = x1 - mu, d2 = x2 - mu, d3 = x3 - mu;
    red[tid] = d0 * d0 + d1 * d1 + d2 * d2 + d3 * d3; __syncthreads();
    for (int o2 = 128; o2 > 0; o2 >>= 1) {
        if (tid < o2) red[tid] += red[tid + o2];
        __syncthreads();
    }
    float inv = rsqrtf(red[0] * (1.0f / E_) + 1e-12f);
    float4 g4 = *(const float4*)(gamma + off);
    float4 b4 = *(const float4*)(beta + off);
    float4 o4;
    o4.x = d0 * inv * g4.x + b4.x;
    o4.y = d1 * inv * g4.y + b4.y;
    o4.z = d2 * inv * g4.z + b4.z;
    o4.w = d3 * inv * g4.w + b4.w;
    *(float4*)(outp + rowbase + off) = o4;
}

extern "C" void kernel_launch(void* const* d_in, const int* in_sizes, int n_in,
                              void* d_out, int out_size, void* d_ws, size_t ws_size,
                              hipStream_t stream) {
    const float* emb    = (const float*)d_in[0];
    const float* W1     = (const float*)d_in[1];
    const float* b1     = (const float*)d_in[2];
    const float* W2     = (const float*)d_in[3];
    const float* b2     = (const float*)d_in[4];
    const float* psfs   = (const float*)d_in[5];
    const float* W3     = (const float*)d_in[6];
    const float* b3     = (const float*)d_in[7];
    const float* sparse = (const float*)d_in[8];
    const float* gamma  = (const float*)d_in[9];
    const float* beta   = (const float*)d_in[10];
    float* outp = (float*)d_out;

    const size_t BLE  = (size_t)B_ * L_ * E_;
    const size_t EE   = (size_t)E_ * E_;
    const size_t KSZ  = (size_t)H_ * D_ * NFFT;        // f16x2 elems
    const size_t XVSZ = (size_t)B_ * H_ * 33 * L_;     // f16x2 elems

    bf16*   accbb      = (bf16*)d_ws;                  // 16.8 MB
    bf16*   pre_sparse = accbb + BLE;                  // 16.8 MB
    f16x2*  Khat       = (f16x2*)(pre_sparse + BLE);   // 16.8 MB
    f16x2*  Xv         = Khat + KSZ;                   // 17.3 MB
    bf16*   preb       = (bf16*)(Xv + XVSZ);           // 16.8 MB
    bf16*   actb       = preb + BLE;                   // 16.8 MB
    bf16*   W1b        = actb + BLE;                   // 3x 2.1 MB
    bf16*   W2b        = W1b + EE;
    bf16*   W3b        = W2b + EE;
    float2* twd        = (float2*)(W3b + EE);          // 32 KB
    int*    s_nnz      = (int*)(twd + NFFT);           // dedicated region (~2MB)
    int*    s_idx      = s_nnz + L_;
    float*  s_val      = (float*)(s_idx + (size_t)L_ * CAP);
    // psfT overlays Xv (dead before vfft writes Xv)
    float*  psfT       = (float*)Xv;

    // prologue: twiddle | emb->bf16 | W1..3->bf16 | psf transpose | sparse lists
    k_prologue<<<NB_TW + NB_CVT + NB_CVTW + NB_TF + NB_SP, 256, 0, stream>>>(
        emb, W1, W2, W3, psfs, sparse, twd, actb, W1b, psfT, s_nnz, s_idx, s_val);

    // merged: preb = bf16(emb @ W1^T + b1)  ||  build_khat
    k_gemm1_khat<<<2048, 256, 0, stream>>>(actb, W1b, b1, preb, psfT, Khat, twd);

    // merged: pre_sparse = GEMM2 || dfft(Khat) || vfft(preb)
    k_gemm2_dfft_vfft<<<4096, 256, 0, stream>>>(preb, W2b, b2, pre_sparse, Khat, Xv, twd);

    // fused per-(k,h,b) seq conv (in place)
    k_seqconv<<<dim3(33, H_, B_), 256, 0, stream>>>(Xv, Khat, twd);

    // inverse v-FFT + GELU -> actb
    k_vifft<<<dim3(L_ / 64, H_, B_), 256, 0, stream>>>(Xv, actb, twd);

    // accbb = bf16(conv @ W3^T + b3)
    k_gemm3<<<1024, 256, 0, stream>>>(actb, W3b, b3, accbb);

    // fused: out = LayerNorm(accbb + tril(sparse)@pre_sparse + emb)
    k_spmm_ln<<<dim3(L_, B_), 256, 0, stream>>>(
        s_nnz, s_idx, s_val, pre_sparse, accbb, emb, gamma, beta, outp);
}